// Round 8
// baseline (701.071 us; speedup 1.0000x reference)
//
#include <hip/hip_runtime.h>
#include <hip/hip_bf16.h>
#include <stdint.h>
#include <stddef.h>

typedef __bf16 bf16_t;
typedef __bf16 bf16x4 __attribute__((ext_vector_type(4)));
typedef __bf16 bf16x8 __attribute__((ext_vector_type(8)));
typedef float  f32x4  __attribute__((ext_vector_type(4)));

#define Bsz  4
#define Ssz  2048
#define Dsz  768
#define Isz  1536
#define Hn   8
#define HDsz 64
#define NTOK (Bsz*Ssz)      /* 8192 */
#define Lc   64
#define NCH  (Ssz/Lc)       /* 32 */
#define NBH  (Bsz*Hn)       /* 32 */

/* ---------------- workspace layout (bytes) ---------------- */
#define OFF_H      ((size_t)0)
#define OFF_WUPT   ((size_t)12582912)
#define OFF_WQKVO  ((size_t)14942208)
#define OFF_WOUTB  ((size_t)21233664)             /* W_out bf16 (512x1536) */
#define OFF_WDOWNT ((size_t)22806528)
#define OFF_U      ((size_t)25165824)
#define OFF_QKVO   ((size_t)50331648)
#define OFF_KT     ((size_t)83886080)
#define OFF_VT     ((size_t)92274688)
#define OFF_IFB    ((size_t)100663296)
#define OFF_BLOC   ((size_t)101187584)
#define OFF_MHAT   ((size_t)101449728)
#define OFF_MST    ((size_t)101711872)
#define OFF_DEC    ((size_t)101715968)
#define OFF_MEND   ((size_t)101720064)
#define OFF_NG     ((size_t)101724160)
#define OFF_NST    ((size_t)101986304)
#define OFF_WIFT   ((size_t)102248448)
#define OFF_WOC    ((size_t)102297600)            /* WocT bf16 (768x512) */
/* aliases */
#define OFF_CSTB   ((size_t)0)
#define OFF_HT     OFF_U
#define OFF_G      OFF_U
#define OFF_GATED  (OFF_U + 16777216)

/* ---------------- helpers ---------------- */
__device__ __forceinline__ void gload16(const void* gsrc, void* ldst) {
  __builtin_amdgcn_global_load_lds(
      (const __attribute__((address_space(1))) void*)gsrc,
      (__attribute__((address_space(3))) void*)ldst, 16, 0, 0);
}

__device__ __forceinline__ float blockReduceSum256(float v) {
  #pragma unroll
  for (int o = 1; o < 64; o <<= 1) v += __shfl_xor(v, o, 64);
  __shared__ float sh[4];
  int wid = threadIdx.x >> 6;
  __syncthreads();
  if ((threadIdx.x & 63) == 0) sh[wid] = v;
  __syncthreads();
  return sh[0] + sh[1] + sh[2] + sh[3];
}

/* ---------------- weight transpose+cast ---------------- */
__global__ __launch_bounds__(256) void transpose_cast(const float* __restrict__ W,
                                                      bf16_t* __restrict__ Wt,
                                                      int K, int N, float scale) {
  __shared__ float tile[32][33];
  int n0 = blockIdx.x * 32, k0 = blockIdx.y * 32;
  int tx = threadIdx.x, ty = threadIdx.y;
  #pragma unroll
  for (int j = 0; j < 32; j += 8)
    tile[ty + j][tx] = W[(size_t)(k0 + ty + j) * N + n0 + tx];
  __syncthreads();
  #pragma unroll
  for (int j = 0; j < 32; j += 8)
    Wt[(size_t)(n0 + ty + j) * K + k0 + tx] = (bf16_t)(tile[tx][ty + j] * scale);
}

/* ---------------- plain f32 -> bf16 cast (row-major preserved) ---------------- */
__global__ __launch_bounds__(256) void cast_bf16(const float* __restrict__ W,
                                                 bf16_t* __restrict__ Wb, int n) {
  int i = blockIdx.x * 256 + threadIdx.x;
  if (i < n) Wb[i] = (bf16_t)W[i];
}

/* ---------------- build WifT ---------------- */
__global__ __launch_bounds__(256) void build_wift(const float* __restrict__ Wi,
                                                  const float* __restrict__ Wf,
                                                  bf16_t* __restrict__ WifT) {
  int idx = blockIdx.x * 256 + threadIdx.x;
  if (idx < 16 * 1536) {
    int n = idx / 1536, k = idx - n * 1536;
    float v = (n < 8) ? Wi[(size_t)k * 8 + n] : Wf[(size_t)k * 8 + (n - 8)];
    WifT[idx] = (bf16_t)v;
  }
}

/* ---------------- LayerNorm ---------------- */
__global__ __launch_bounds__(256) void ln_kernel(const float* __restrict__ x,
                                                 const float* __restrict__ g,
                                                 const float* __restrict__ bta,
                                                 bf16_t* __restrict__ h) {
  size_t tok = blockIdx.x;
  const float* xr = x + tok * Dsz;
  int t = threadIdx.x;
  float v[3]; float s = 0.f;
  #pragma unroll
  for (int i = 0; i < 3; ++i) { v[i] = xr[t + 256 * i]; s += v[i]; }
  s = blockReduceSum256(s);
  float mu = s * (1.f / Dsz);
  float s2 = 0.f;
  #pragma unroll
  for (int i = 0; i < 3; ++i) { float d = v[i] - mu; s2 += d * d; }
  s2 = blockReduceSum256(s2);
  float rs = rsqrtf(s2 * (1.f / Dsz) + 1e-5f);
  #pragma unroll
  for (int i = 0; i < 3; ++i) {
    int col = t + 256 * i;
    h[tok * Dsz + col] = (bf16_t)((v[i] - mu) * rs * g[col] + bta[col]);
  }
}

/* ======================================================================
   256M x 128N m97-style GEMM: C(M,N) = A(M,K) @ Bt(N,K)^T
   512 threads = 8 waves (4M x 2N); BK=64; single-buffer 48 KiB LDS;
   multi-block overlap (3 blocks/CU LDS-limited; launch_bounds(512,6)).
   128B-row XOR swizzle: byte ^= (row&7)<<4, pre-swizzled global source.
   EPI: 0 = bf16 out; 3 = f32 out + resid; 4 = qkvo (col>=1536: sigmoid).
   ====================================================================== */
template<int EPI>
__global__ __launch_bounds__(512, 6) void gemm_mn(const bf16_t* __restrict__ A,
                                                  const bf16_t* __restrict__ Bt,
                                                  void* __restrict__ Cout,
                                                  const void* __restrict__ extra,
                                                  int M, int N, int K) {
  __shared__ bf16_t As[256 * 64];
  __shared__ bf16_t Bs[128 * 64];
  const int t = threadIdx.x;
  const int w = t >> 6, l = t & 63;
  const int wm = w >> 1, wn = w & 1;
  const int l15 = l & 15, l4 = l >> 4;

  /* bijective XCD swizzle (nwg % 8 == 0 for all launches) */
  const int gx = gridDim.x;
  const int nwg = gx * gridDim.y;
  const int cpx = nwg >> 3;
  int bid = blockIdx.y * gx + blockIdx.x;
  int wg = (bid & 7) * cpx + (bid >> 3);
  const int tile_m = (wg / gx) * 256;
  const int tile_n = (wg % gx) * 128;

  f32x4 acc[4][4];
  #pragma unroll
  for (int m = 0; m < 4; ++m)
    #pragma unroll
    for (int n = 0; n < 4; ++n) acc[m][n] = (f32x4){0.f, 0.f, 0.f, 0.f};

  for (int k0 = 0; k0 < K; k0 += 64) {
    #pragma unroll
    for (int j = 0; j < 4; ++j) {
      int c = t + j * 512;
      int row = c >> 3;
      int ec = ((c & 7) * 8) ^ ((row & 7) << 3);
      gload16(A + (size_t)(tile_m + row) * K + k0 + ec, (char*)As + (size_t)c * 16);
    }
    #pragma unroll
    for (int j = 0; j < 2; ++j) {
      int c = t + j * 512;
      int row = c >> 3;
      int ec = ((c & 7) * 8) ^ ((row & 7) << 3);
      gload16(Bt + (size_t)(tile_n + row) * K + k0 + ec, (char*)Bs + (size_t)c * 16);
    }
    __syncthreads();
    #pragma unroll
    for (int kk = 0; kk < 2; ++kk) {
      bf16x8 aF[4], bF[4];
      #pragma unroll
      for (int m = 0; m < 4; ++m) {
        int r = wm * 64 + m * 16 + l15;
        aF[m] = *(const bf16x8*)((const char*)As + r * 128 + ((kk * 64 + l4 * 16) ^ ((r & 7) << 4)));
      }
      #pragma unroll
      for (int n = 0; n < 4; ++n) {
        int r = wn * 64 + n * 16 + l15;
        bF[n] = *(const bf16x8*)((const char*)Bs + r * 128 + ((kk * 64 + l4 * 16) ^ ((r & 7) << 4)));
      }
      #pragma unroll
      for (int m = 0; m < 4; ++m)
        #pragma unroll
        for (int n = 0; n < 4; ++n)
          acc[m][n] = __builtin_amdgcn_mfma_f32_16x16x32_bf16(aF[m], bF[n], acc[m][n], 0, 0, 0);
    }
    __syncthreads();
  }

  const int rbase = tile_m + wm * 64 + l4 * 4;
  const int cbase = tile_n + wn * 64 + l15;
  #pragma unroll
  for (int m = 0; m < 4; ++m)
    #pragma unroll
    for (int n = 0; n < 4; ++n)
      #pragma unroll
      for (int j = 0; j < 4; ++j) {
        int row = rbase + m * 16 + j;
        int col = cbase + n * 16;
        float v = acc[m][n][j];
        if constexpr (EPI == 0) {
          ((bf16_t*)Cout)[(size_t)row * N + col] = (bf16_t)v;
        } else if constexpr (EPI == 3) {
          ((float*)Cout)[(size_t)row * N + col] =
              v + ((const float*)extra)[(size_t)row * N + col];
        } else {  /* EPI == 4 */
          if (col < 1536) {
            ((bf16_t*)Cout)[(size_t)row * N + col] = (bf16_t)v;
          } else {
            float z = v + ((const float*)extra)[col - 1536];
            ((bf16_t*)Cout)[(size_t)row * N + col] = (bf16_t)(1.f / (1.f + __expf(-z)));
          }
        }
      }
}

/* ---------------- 128^2 MFMA GEMM (W_oc precompute): EPI 0 bf16 out ---------------- */
template<int EPI>
__global__ __launch_bounds__(256) void gemm_bt(const bf16_t* __restrict__ A,
                                               const bf16_t* __restrict__ Bt,
                                               void* __restrict__ Cout,
                                               const void* __restrict__ extra,
                                               int M, int N, int K) {
  __shared__ bf16_t As[128 * 64];
  __shared__ bf16_t Bs[128 * 64];
  const int t = threadIdx.x;
  const int w = t >> 6, l = t & 63;
  const int tile_m = blockIdx.y * 128, tile_n = blockIdx.x * 128;
  const int wr = w >> 1, wc = w & 1;
  const int lrow = l >> 3;
  const int lks = ((l & 7) * 8) ^ (lrow << 3);
  const int l15 = l & 15, l4 = l >> 4;

  f32x4 acc[4][4];
  #pragma unroll
  for (int m = 0; m < 4; ++m)
    #pragma unroll
    for (int n = 0; n < 4; ++n) acc[m][n] = (f32x4){0.f, 0.f, 0.f, 0.f};

  for (int k0 = 0; k0 < K; k0 += 64) {
    #pragma unroll
    for (int i = 0; i < 4; ++i) {
      int ch = w * 4 + i;
      int row = ch * 8 + lrow;
      gload16(A  + (size_t)(tile_m + row) * K + k0 + lks, &As[ch * 512]);
      gload16(Bt + (size_t)(tile_n + row) * K + k0 + lks, &Bs[ch * 512]);
    }
    __syncthreads();
    #pragma unroll
    for (int kk = 0; kk < 2; ++kk) {
      bf16x8 af[4], bfr[4];
      #pragma unroll
      for (int m = 0; m < 4; ++m) {
        int r = wr * 64 + m * 16 + l15;
        af[m] = *(const bf16x8*)&As[r * 64 + ((kk * 32 + l4 * 8) ^ ((r & 7) << 3))];
      }
      #pragma unroll
      for (int n = 0; n < 4; ++n) {
        int r = wc * 64 + n * 16 + l15;
        bfr[n] = *(const bf16x8*)&Bs[r * 64 + ((kk * 32 + l4 * 8) ^ ((r & 7) << 3))];
      }
      #pragma unroll
      for (int m = 0; m < 4; ++m)
        #pragma unroll
        for (int n = 0; n < 4; ++n)
          acc[m][n] = __builtin_amdgcn_mfma_f32_16x16x32_bf16(af[m], bfr[n], acc[m][n], 0, 0, 0);
    }
    __syncthreads();
  }

  const int rbase = tile_m + wr * 64 + l4 * 4;
  const int cbase = tile_n + wc * 64 + l15;
  #pragma unroll
  for (int m = 0; m < 4; ++m)
    #pragma unroll
    for (int n = 0; n < 4; ++n)
      #pragma unroll
      for (int j = 0; j < 4; ++j) {
        int row = rbase + m * 16 + j;
        int col = cbase + n * 16;
        float v = acc[m][n][j];
        if constexpr (EPI == 0) {
          ((bf16_t*)Cout)[(size_t)row * N + col] = (bf16_t)v;
        } else {
          ((float*)Cout)[(size_t)row * N + col] =
              v + ((const float*)extra)[(size_t)row * N + col];
        }
      }
}

/* ---------------- i/f gate projection MFMA GEMM: M=8192 N=16 K=1536 ---------------- */
__global__ __launch_bounds__(256) void ifproj_mfma(const bf16_t* __restrict__ u,
                                                   const bf16_t* __restrict__ WifT,
                                                   const float* __restrict__ bi,
                                                   const float* __restrict__ bfv,
                                                   float* __restrict__ ifb) {
  __shared__ bf16_t As[128 * 64];
  __shared__ bf16_t Bs[16 * 64];
  const int t = threadIdx.x, w = t >> 6, l = t & 63;
  const int l15 = l & 15, l4 = l >> 4;
  const int lrow = l >> 3, lk = (l & 7) * 8;
  const int tile_m = blockIdx.x * 128;
  f32x4 acc[2];
  acc[0] = (f32x4){0.f, 0.f, 0.f, 0.f};
  acc[1] = (f32x4){0.f, 0.f, 0.f, 0.f};

  for (int k0 = 0; k0 < Isz; k0 += 64) {
    #pragma unroll
    for (int i = 0; i < 4; ++i) {
      int ch = w * 4 + i;
      int row = ch * 8 + lrow;
      gload16(u + (size_t)(tile_m + row) * Isz + k0 + lk, &As[ch * 512]);
    }
    if (t < 128) {
      int rr = t >> 3, c0 = (t & 7) * 8;
      *(bf16x8*)&Bs[rr * 64 + c0] = *(const bf16x8*)(WifT + (size_t)rr * Isz + k0 + c0);
    }
    __syncthreads();
    #pragma unroll
    for (int kk = 0; kk < 2; ++kk) {
      bf16x8 bfr = *(const bf16x8*)&Bs[l15 * 64 + kk * 32 + l4 * 8];
      #pragma unroll
      for (int m = 0; m < 2; ++m) {
        bf16x8 af = *(const bf16x8*)&As[(w * 32 + m * 16 + l15) * 64 + kk * 32 + l4 * 8];
        acc[m] = __builtin_amdgcn_mfma_f32_16x16x32_bf16(af, bfr, acc[m], 0, 0, 0);
      }
    }
    __syncthreads();
  }
  float bias = (l15 < 8) ? bi[l15] : bfv[l15 - 8];
  #pragma unroll
  for (int m = 0; m < 2; ++m)
    #pragma unroll
    for (int j = 0; j < 4; ++j) {
      int row = tile_m + w * 32 + m * 16 + l4 * 4 + j;
      ifb[(size_t)row * 16 + l15] = acc[m][j] + bias;
    }
}

/* ---------------- gates pass A ---------------- */
__global__ __launch_bounds__(64) void gates_a(const float* __restrict__ ifb,
                                              float* __restrict__ blocal,
                                              float* __restrict__ Mhat) {
  int bh = blockIdx.x >> 5, c = blockIdx.x & 31;
  int b = bh >> 3, h = bh & 7;
  int lane = threadIdx.x;
  size_t tok = (size_t)b * Ssz + c * Lc + lane;
  float iv = ifb[tok * 16 + h];
  float fv = ifb[tok * 16 + 8 + h];
  float bt = fv;
  #pragma unroll
  for (int d = 1; d < 64; d <<= 1) { float o = __shfl_up(bt, d, 64); if (lane >= d) bt += o; }
  float a = iv - bt;
  float pm = a;
  #pragma unroll
  for (int d = 1; d < 64; d <<= 1) { float o = __shfl_up(pm, d, 64); if (lane >= d) pm = fmaxf(pm, o); }
  blocal[(size_t)bh * Ssz + c * Lc + lane] = bt;
  Mhat[(size_t)bh * Ssz + c * Lc + lane] = bt + pm;
}

/* ---------------- gates pass B ---------------- */
__global__ void gates_b(const float* __restrict__ blocal, const float* __restrict__ Mhat,
                        float* __restrict__ mstart, float* __restrict__ decays,
                        float* __restrict__ mend) {
  int bh = threadIdx.x;
  if (bh < NBH) {
    float M = 0.f;
    for (int c = 0; c < NCH; ++c) {
      mstart[bh * NCH + c] = M;
      float bL = blocal[(size_t)bh * Ssz + c * Lc + 63];
      float Mh = Mhat[(size_t)bh * Ssz + c * Lc + 63];
      float Mn = fmaxf(M + bL, Mh);
      decays[bh * NCH + c] = __expf(M + bL - Mn);
      mend[bh * NCH + c] = Mn;
      M = Mn;
    }
  }
}

/* ---------------- k/v transpose ---------------- */
__global__ __launch_bounds__(256) void kv_transpose(const bf16_t* __restrict__ qkvo,
                                                    bf16_t* __restrict__ kTg,
                                                    bf16_t* __restrict__ vTg) {
  int bh = blockIdx.x >> 5, st = blockIdx.x & 31;
  int b = bh >> 3, h = bh & 7;
  __shared__ bf16_t Lk[64 * 72];
  __shared__ bf16_t Lv[64 * 72];
  int t = threadIdx.x;
  size_t tok0 = (size_t)b * Ssz + st * 64;
  #pragma unroll
  for (int i = 0; i < 2; ++i) {
    int e = t + i * 256; int r = e >> 3, c0 = (e & 7) * 8;
    bf16x8 kv = *(const bf16x8*)(qkvo + (tok0 + r) * 2048 + 512 + h * 64 + c0);
    bf16x8 vv = *(const bf16x8*)(qkvo + (tok0 + r) * 2048 + 1024 + h * 64 + c0);
    *(bf16x8*)&Lk[r * 72 + c0] = kv;
    *(bf16x8*)&Lv[r * 72 + c0] = vv;
  }
  __syncthreads();
  #pragma unroll
  for (int i = 0; i < 2; ++i) {
    int e = t + i * 256; int d = e >> 3, s0 = (e & 7) * 8;
    bf16x8 ok, ov;
    #pragma unroll
    for (int j = 0; j < 8; ++j) {
      ok[j] = Lk[(s0 + j) * 72 + d];
      ov[j] = Lv[(s0 + j) * 72 + d];
    }
    *(bf16x8*)(kTg + ((size_t)bh * 64 + d) * Ssz + st * 64 + s0) = ok;
    *(bf16x8*)(vTg + ((size_t)bh * 64 + d) * Ssz + st * 64 + s0) = ov;
  }
}

/* ---------------- per-chunk state increment, MFMA ---------------- */
__global__ __launch_bounds__(256) void chunk_inc_mfma(const bf16_t* __restrict__ kTg,
                                                      const bf16_t* __restrict__ vTg,
                                                      const float* __restrict__ ifb,
                                                      const float* __restrict__ blocal,
                                                      const float* __restrict__ mend,
                                                      bf16_t* __restrict__ G,
                                                      float* __restrict__ ng) {
  int bh = blockIdx.x >> 5, c = blockIdx.x & 31;
  int b = bh >> 3, h = bh & 7;
  __shared__ bf16_t Vt[64 * 64];
  __shared__ bf16_t Kw[64 * 64];
  __shared__ float wsh[64];
  const int t = threadIdx.x, w = t >> 6, l = t & 63;
  const int l15 = l & 15, l4 = l >> 4;
  if (t < 64) {
    float mL = mend[bh * NCH + c];
    float bL = blocal[(size_t)bh * Ssz + c * Lc + 63];
    float bt = blocal[(size_t)bh * Ssz + c * Lc + t];
    float iv = ifb[((size_t)b * Ssz + c * Lc + t) * 16 + h];
    wsh[t] = __expf(iv + bL - bt - mL);
  }
  __syncthreads();
  {
    const int r = l >> 3, c8 = (l & 7) * 8;
    #pragma unroll
    for (int i = 0; i < 2; ++i) {
      int seg = w * 2 + i, row = seg * 8 + r;
      gload16(vTg + ((size_t)bh * 64 + row) * Ssz + c * 64 + c8, &Vt[seg * 512]);
    }
    #pragma unroll
    for (int i = 0; i < 2; ++i) {
      int e = t + i * 256; int row = e >> 3, c0 = (e & 7) * 8;
      bf16x8 kv = *(const bf16x8*)(kTg + ((size_t)bh * 64 + row) * Ssz + c * 64 + c0);
      #pragma unroll
      for (int j = 0; j < 8; ++j) kv[j] = (bf16_t)((float)kv[j] * wsh[c0 + j]);
      *(bf16x8*)&Kw[row * 64 + c0] = kv;
    }
  }
  __syncthreads();
  f32x4 acc[4];
  #pragma unroll
  for (int n = 0; n < 4; ++n) acc[n] = (f32x4){0.f, 0.f, 0.f, 0.f};
  #pragma unroll
  for (int kk = 0; kk < 2; ++kk) {
    bf16x8 af = *(const bf16x8*)&Vt[(w * 16 + l15) * 64 + kk * 32 + l4 * 8];
    #pragma unroll
    for (int n = 0; n < 4; ++n) {
      bf16x8 bfr = *(const bf16x8*)&Kw[(n * 16 + l15) * 64 + kk * 32 + l4 * 8];
      acc[n] = __builtin_amdgcn_mfma_f32_16x16x32_bf16(af, bfr, acc[n], 0, 0, 0);
    }
  }
  size_t gb = ((size_t)bh * NCH + c) * 4096;
  #pragma unroll
  for (int n = 0; n < 4; ++n)
    #pragma unroll
    for (int j = 0; j < 4; ++j) {
      int row = w * 16 + l4 * 4 + j;
      int col = n * 16 + l15;
      G[gb + (size_t)row * 64 + col] = (bf16_t)acc[n][j];
    }
  if (t < 64) {
    float s = 0.f;
    for (int s2 = 0; s2 < 64; ++s2) s += (float)Kw[t * 64 + s2];
    ng[((size_t)bh * NCH + c) * 64 + t] = s;
  }
}

/* ---------------- state scan ---------------- */
__global__ __launch_bounds__(256) void state_scan(const bf16_t* __restrict__ G,
                                                  const float* __restrict__ ng,
                                                  const float* __restrict__ decays,
                                                  bf16_t* __restrict__ CstB,
                                                  float* __restrict__ nst) {
  int gid = blockIdx.x;
  if (gid < 512) {
    int idx = gid * 256 + threadIdx.x;
    int bh = idx >> 12, e = idx & 4095;
    const float* d = decays + bh * NCH;
    float C = 0.f;
    #pragma unroll
    for (int c = 0; c < NCH; ++c) {
      size_t o = ((size_t)bh * NCH + c) * 4096 + e;
      CstB[o] = (bf16_t)C;
      C = d[c] * C + (float)G[o];
    }
  } else {
    int idx = (gid - 512) * 256 + threadIdx.x;
    int bh = idx >> 6, e = idx & 63;
    const float* d = decays + bh * NCH;
    float n = 0.f;
    #pragma unroll
    for (int c = 0; c < NCH; ++c) {
      size_t o = ((size_t)bh * NCH + c) * 64 + e;
      nst[o] = n;
      n = d[c] * n + ng[o];
    }
  }
}

/* ---------------- intra-chunk outputs, MFMA ---------------- */
__global__ __launch_bounds__(256) void intra_mfma(const bf16_t* __restrict__ qkvo,
                                                  const bf16_t* __restrict__ vTg,
                                                  const bf16_t* __restrict__ CstB,
                                                  const float* __restrict__ nst,
                                                  const float* __restrict__ ifb,
                                                  const float* __restrict__ blocal,
                                                  const float* __restrict__ Mhat,
                                                  const float* __restrict__ mstart,
                                                  float* __restrict__ ht) {
  int bh = blockIdx.x >> 5, c = blockIdx.x & 31;
  int b = bh >> 3, h = bh & 7;
  __shared__ bf16_t qs[64 * 64];
  __shared__ bf16_t ks[64 * 64];
  __shared__ bf16_t vTs[64 * 64];
  __shared__ bf16_t Cs[64 * 64];
  __shared__ float nin[64], den_s[64], ssrc[64], sdst[64], esc[64];
  const int t = threadIdx.x, w = t >> 6, l = t & 63;
  const int l15 = l & 15, l4 = l >> 4;
  const size_t tok0 = (size_t)b * Ssz + c * Lc;
  const size_t cbase = ((size_t)bh * NCH + c) * 4096;

  if (t < 64) {
    nin[t] = nst[((size_t)bh * NCH + c) * 64 + t];
    float bt = blocal[(size_t)bh * Ssz + c * Lc + t];
    float Mh2 = Mhat[(size_t)bh * Ssz + c * Lc + t];
    float Mc = mstart[bh * NCH + c];
    float iv = ifb[(tok0 + t) * 16 + h];
    float mt = fmaxf(Mc + bt, Mh2);
    ssrc[t] = iv - bt;
    sdst[t] = bt - mt;
    esc[t]  = __expf(Mc + bt - mt);
  }
  {
    const int r = l >> 3, c8 = (l & 7) * 8;
    #pragma unroll
    for (int i = 0; i < 2; ++i) {
      int seg = w * 2 + i, row = seg * 8 + r;
      gload16(qkvo + (tok0 + row) * 2048 + h * 64 + c8,          &qs[seg * 512]);
      gload16(qkvo + (tok0 + row) * 2048 + 512 + h * 64 + c8,    &ks[seg * 512]);
      gload16(vTg + ((size_t)bh * 64 + row) * Ssz + c * 64 + c8, &vTs[seg * 512]);
      gload16(CstB + cbase + seg * 512 + l * 8,                  &Cs[seg * 512]);
    }
  }
  __syncthreads();

  f32x4 aS[4];
  #pragma unroll
  for (int n = 0; n < 4; ++n) aS[n] = (f32x4){0.f, 0.f, 0.f, 0.f};
  #pragma unroll
  for (int kk = 0; kk < 2; ++kk) {
    bf16x8 af = *(const bf16x8*)&qs[(w * 16 + l15) * 64 + kk * 32 + l4 * 8];
    #pragma unroll
    for (int n = 0; n < 4; ++n) {
      bf16x8 bfr = *(const bf16x8*)&ks[(n * 16 + l15) * 64 + kk * 32 + l4 * 8];
      aS[n] = __builtin_amdgcn_mfma_f32_16x16x32_bf16(af, bfr, aS[n], 0, 0, 0);
    }
  }
  {
    int row = w * 16 + (l >> 2);
    int c0 = (l & 3) * 16;
    float e = esc[row];
    #pragma unroll
    for (int i2 = 0; i2 < 2; ++i2) {
      bf16x8 v8 = *(const bf16x8*)&qs[row * 64 + c0 + i2 * 8];
      #pragma unroll
      for (int j = 0; j < 8; ++j) v8[j] = (bf16_t)((float)v8[j] * e);
      *(bf16x8*)&qs[row * 64 + c0 + i2 * 8] = v8;
    }
  }
  float rs[4] = {0.f, 0.f, 0.f, 0.f};
  #pragma unroll
  for (int n = 0; n < 4; ++n) {
    int col = n * 16 + l15;
    float es = ssrc[col];
    #pragma unroll
    for (int j = 0; j < 4; ++j) {
      int row = w * 16 + l4 * 4 + j;
      float p = (col <= row) ? aS[n][j] * __expf(es + sdst[row]) : 0.f;
      aS[n][j] = p;
      rs[j] += p;
    }
  }
  #pragma unroll
  for (int j = 0; j < 4; ++j) {
    rs[j] += __shfl_xor(rs[j], 1, 64);
    rs[j] += __shfl_xor(rs[j], 2, 64);
    rs[j] += __shfl_xor(rs[j], 4, 64);
    rs[j] += __shfl_xor(rs[j], 8, 64);
  }
  if (l15 == 0) {
    #pragma unroll
    for (int j = 0; j < 4; ++j) den_s[w * 16 + l4 * 4 + j] = rs[j];
  }
  __syncthreads();

  #pragma unroll
  for (int n = 0; n < 4; ++n)
    #pragma unroll
    for (int j = 0; j < 4; ++j)
      ks[(w * 16 + l4 * 4 + j) * 64 + n * 16 + l15] = (bf16_t)aS[n][j];

  {
    int row = w * 16 + (l >> 2);
    int c0 = (l & 3) * 16;
    float part = 0.f;
    #pragma unroll
    for (int i2 = 0; i2 < 16; ++i2)
      part += (float)qs[row * 64 + c0 + i2] * nin[c0 + i2];
    part += __shfl_xor(part, 1, 64);
    part += __shfl_xor(part, 2, 64);
    if ((l & 3) == 0)
      den_s[row] = fmaxf(fabsf(den_s[row] + part), 1.0f);
  }
  __syncthreads();

  f32x4 aO[4];
  #pragma unroll
  for (int n = 0; n < 4; ++n) aO[n] = (f32x4){0.f, 0.f, 0.f, 0.f};
  #pragma unroll
  for (int kk = 0; kk < 2; ++kk) {
    bf16x8 afP = *(const bf16x8*)&ks[(w * 16 + l15) * 64 + kk * 32 + l4 * 8];
    bf16x8 afQ = *(const bf16x8*)&qs[(w * 16 + l15) * 64 + kk * 32 + l4 * 8];
    #pragma unroll
    for (int n = 0; n < 4; ++n) {
      bf16x8 bV = *(const bf16x8*)&vTs[(n * 16 + l15) * 64 + kk * 32 + l4 * 8];
      bf16x8 bC = *(const bf16x8*)&Cs[(n * 16 + l15) * 64 + kk * 32 + l4 * 8];
      aO[n] = __builtin_amdgcn_mfma_f32_16x16x32_bf16(afP, bV, aO[n], 0, 0, 0);
      aO[n] = __builtin_amdgcn_mfma_f32_16x16x32_bf16(afQ, bC, aO[n], 0, 0, 0);
    }
  }
  #pragma unroll
  for (int j = 0; j < 4; ++j) {
    int row = w * 16 + l4 * 4 + j;
    float rinv = 1.f / den_s[row];
    size_t rowg = ((tok0 + row) * Hn + h) * HDsz;
    #pragma unroll
    for (int n = 0; n < 4; ++n)
      ht[rowg + n * 16 + l15] = aO[n][j] * rinv;
  }
}

/* ---------------- group-norm + output gate ---------------- */
__global__ __launch_bounds__(256) void gn_gate(const float* __restrict__ ht,
                                               const bf16_t* __restrict__ qkvo,
                                               const float* __restrict__ mhg,
                                               bf16_t* __restrict__ gated) {
  int gid = blockIdx.x * 4 + (threadIdx.x >> 6);
  int lane = threadIdx.x & 63;
  int h = gid & 7;
  size_t tok = (size_t)(gid >> 3);
  size_t idx = (size_t)gid * 64 + lane;
  float v = ht[idx];
  float s = v;
  #pragma unroll
  for (int o = 1; o < 64; o <<= 1) s += __shfl_xor(s, o, 64);
  float mu = s * (1.f / 64.f);
  float d = v - mu;
  float s2 = d * d;
  #pragma unroll
  for (int o = 1; o < 64; o <<= 1) s2 += __shfl_xor(s2, o, 64);
  float hn = d * rsqrtf(s2 * (1.f / 64.f) + 1e-5f) * mhg[h * 64 + lane];
  float og = (float)qkvo[tok * 2048 + 1536 + h * 64 + lane];
  gated[idx] = (bf16_t)(og * hn);
}

/* ---------------- launcher ---------------- */
extern "C" void kernel_launch(void* const* d_in, const int* in_sizes, int n_in,
                              void* d_out, int out_size, void* d_ws, size_t ws_size,
                              hipStream_t stream) {
  const float* x     = (const float*)d_in[0];
  const float* ln_g  = (const float*)d_in[1];
  const float* ln_b  = (const float*)d_in[2];
  const float* W_up  = (const float*)d_in[3];
  const float* W_down= (const float*)d_in[4];
  const float* Wq    = (const float*)d_in[5];
  const float* Wk    = (const float*)d_in[6];
  const float* Wv    = (const float*)d_in[7];
  const float* Wi    = (const float*)d_in[8];
  const float* bi    = (const float*)d_in[9];
  const float* Wf    = (const float*)d_in[10];
  const float* bfv   = (const float*)d_in[11];
  const float* Wo    = (const float*)d_in[12];
  const float* bo    = (const float*)d_in[13];
  const float* mh_g  = (const float*)d_in[14];
  const float* W_out = (const float*)d_in[15];

  char* ws = (char*)d_ws;
  bf16_t* hbuf   = (bf16_t*)(ws + OFF_H);
  bf16_t* wupT   = (bf16_t*)(ws + OFF_WUPT);
  bf16_t* wqkvoT = (bf16_t*)(ws + OFF_WQKVO);
  bf16_t* woutB  = (bf16_t*)(ws + OFF_WOUTB);
  bf16_t* wdownT = (bf16_t*)(ws + OFF_WDOWNT);
  bf16_t* ubuf   = (bf16_t*)(ws + OFF_U);
  bf16_t* qkvob  = (bf16_t*)(ws + OFF_QKVO);
  bf16_t* kTg    = (bf16_t*)(ws + OFF_KT);
  bf16_t* vTg    = (bf16_t*)(ws + OFF_VT);
  float*  ifb    = (float*)(ws + OFF_IFB);
  float*  bloc   = (float*)(ws + OFF_BLOC);
  float*  Mh     = (float*)(ws + OFF_MHAT);
  float*  mst    = (float*)(ws + OFF_MST);
  float*  decays = (float*)(ws + OFF_DEC);
  float*  mendb  = (float*)(ws + OFF_MEND);
  float*  ngbuf  = (float*)(ws + OFF_NG);
  float*  nst    = (float*)(ws + OFF_NST);
  bf16_t* wifT   = (bf16_t*)(ws + OFF_WIFT);
  bf16_t* wocT   = (bf16_t*)(ws + OFF_WOC);
  bf16_t* CstB   = (bf16_t*)(ws + OFF_CSTB);
  float*  htbuf  = (float*)(ws + OFF_HT);
  bf16_t* Gbuf   = (bf16_t*)(ws + OFF_G);
  bf16_t* gbuf   = (bf16_t*)(ws + OFF_GATED);

  dim3 tb(32, 8);
  transpose_cast<<<dim3(Isz / 32, Dsz / 32), tb, 0, stream>>>(W_up, wupT, Dsz, Isz, 1.f);
  transpose_cast<<<dim3(512 / 32, Isz / 32), tb, 0, stream>>>(Wq, wqkvoT,                    Isz, 512, 1.f);
  transpose_cast<<<dim3(512 / 32, Isz / 32), tb, 0, stream>>>(Wk, wqkvoT + (size_t)512*Isz,  Isz, 512, 0.125f);
  transpose_cast<<<dim3(512 / 32, Isz / 32), tb, 0, stream>>>(Wv, wqkvoT + (size_t)1024*Isz, Isz, 512, 1.f);
  transpose_cast<<<dim3(512 / 32, Isz / 32), tb, 0, stream>>>(Wo, wqkvoT + (size_t)1536*Isz, Isz, 512, 1.f);
  transpose_cast<<<dim3(Dsz / 32, Isz / 32), tb, 0, stream>>>(W_down, wdownT, Isz, Dsz, 1.f);
  cast_bf16<<<(512 * 1536 + 255) / 256, 256, 0, stream>>>(W_out, woutB, 512 * 1536);
  build_wift<<<96, 256, 0, stream>>>(Wi, Wf, wifT);

  /* WocT(768,512) = wdownT(768,K=1536) @ woutB(512,K=1536)^T  ==  (W_out @ W_down)^T */
  gemm_bt<0><<<dim3(512 / 128, Dsz / 128), 256, 0, stream>>>(wdownT, woutB, wocT, nullptr, Dsz, 512, Isz);

  ln_kernel<<<NTOK, 256, 0, stream>>>(x, ln_g, ln_b, hbuf);

  gemm_mn<0><<<dim3(Isz / 128, NTOK / 256), 512, 0, stream>>>(hbuf, wupT, ubuf, nullptr, NTOK, Isz, Dsz);
  gemm_mn<4><<<dim3(2048 / 128, NTOK / 256), 512, 0, stream>>>(ubuf, wqkvoT, qkvob, bo, NTOK, 2048, Isz);

  ifproj_mfma<<<NTOK / 128, 256, 0, stream>>>(ubuf, wifT, bi, bfv, ifb);
  kv_transpose<<<NBH * NCH, 256, 0, stream>>>(qkvob, kTg, vTg);

  gates_a<<<NBH * NCH, 64, 0, stream>>>(ifb, bloc, Mh);
  gates_b<<<1, 32, 0, stream>>>(bloc, Mh, mst, decays, mendb);
  chunk_inc_mfma<<<NBH * NCH, 256, 0, stream>>>(kTg, vTg, ifb, bloc, mendb, Gbuf, ngbuf);
  state_scan<<<520, 256, 0, stream>>>(Gbuf, ngbuf, decays, CstB, nst);
  intra_mfma<<<NBH * NCH, 256, 0, stream>>>(qkvob, vTg, CstB, nst, ifb, bloc, Mh, mst, htbuf);

  gn_gate<<<NTOK * Hn / 4, 256, 0, stream>>>(htbuf, qkvob, mh_g, gbuf);
  /* fused: out = x + gated @ (W_out @ W_down), K=512 */
  gemm_mn<3><<<dim3(Dsz / 128, NTOK / 256), 512, 0, stream>>>(gbuf, wocT, (float*)d_out, x, NTOK, Dsz, 512);
}

// Round 9
// 234.797 us; speedup vs baseline: 2.9859x; 2.9859x over previous
//
#include <hip/hip_runtime.h>
#include <hip/hip_bf16.h>
#include <stdint.h>
#include <stddef.h>

typedef __bf16 bf16_t;
typedef __bf16 bf16x4 __attribute__((ext_vector_type(4)));
typedef __bf16 bf16x8 __attribute__((ext_vector_type(8)));
typedef float  f32x4  __attribute__((ext_vector_type(4)));

#define Bsz  4
#define Ssz  2048
#define Dsz  768
#define Isz  1536
#define Hn   8
#define HDsz 64
#define NTOK (Bsz*Ssz)      /* 8192 */
#define Lc   64
#define NCH  (Ssz/Lc)       /* 32 */
#define NBH  (Bsz*Hn)       /* 32 */

/* ---------------- workspace layout (bytes) ---------------- */
#define OFF_H      ((size_t)0)
#define OFF_WUPT   ((size_t)12582912)
#define OFF_WQKVO  ((size_t)14942208)
#define OFF_WOUTB  ((size_t)21233664)             /* W_out bf16 (512x1536) */
#define OFF_WDOWNT ((size_t)22806528)
#define OFF_U      ((size_t)25165824)
#define OFF_QKVO   ((size_t)50331648)
#define OFF_KT     ((size_t)83886080)
#define OFF_VT     ((size_t)92274688)
#define OFF_IFB    ((size_t)100663296)
#define OFF_BLOC   ((size_t)101187584)
#define OFF_MHAT   ((size_t)101449728)
#define OFF_MST    ((size_t)101711872)
#define OFF_DEC    ((size_t)101715968)
#define OFF_MEND   ((size_t)101720064)
#define OFF_NG     ((size_t)101724160)
#define OFF_NST    ((size_t)101986304)
#define OFF_WIFT   ((size_t)102248448)
#define OFF_WOC    ((size_t)102297600)            /* WocT bf16 (768x512) */
/* aliases */
#define OFF_CSTB   ((size_t)0)
#define OFF_HT     OFF_U
#define OFF_G      OFF_U
#define OFF_GATED  (OFF_U + 16777216)

/* ---------------- helpers ---------------- */
__device__ __forceinline__ void gload16(const void* gsrc, void* ldst) {
  __builtin_amdgcn_global_load_lds(
      (const __attribute__((address_space(1))) void*)gsrc,
      (__attribute__((address_space(3))) void*)ldst, 16, 0, 0);
}

__device__ __forceinline__ float blockReduceSum256(float v) {
  #pragma unroll
  for (int o = 1; o < 64; o <<= 1) v += __shfl_xor(v, o, 64);
  __shared__ float sh[4];
  int wid = threadIdx.x >> 6;
  __syncthreads();
  if ((threadIdx.x & 63) == 0) sh[wid] = v;
  __syncthreads();
  return sh[0] + sh[1] + sh[2] + sh[3];
}

/* ---------------- weight transpose+cast ---------------- */
__global__ __launch_bounds__(256) void transpose_cast(const float* __restrict__ W,
                                                      bf16_t* __restrict__ Wt,
                                                      int K, int N, float scale) {
  __shared__ float tile[32][33];
  int n0 = blockIdx.x * 32, k0 = blockIdx.y * 32;
  int tx = threadIdx.x, ty = threadIdx.y;
  #pragma unroll
  for (int j = 0; j < 32; j += 8)
    tile[ty + j][tx] = W[(size_t)(k0 + ty + j) * N + n0 + tx];
  __syncthreads();
  #pragma unroll
  for (int j = 0; j < 32; j += 8)
    Wt[(size_t)(n0 + ty + j) * K + k0 + tx] = (bf16_t)(tile[tx][ty + j] * scale);
}

/* ---------------- plain f32 -> bf16 cast ---------------- */
__global__ __launch_bounds__(256) void cast_bf16(const float* __restrict__ W,
                                                 bf16_t* __restrict__ Wb, int n) {
  int i = blockIdx.x * 256 + threadIdx.x;
  if (i < n) Wb[i] = (bf16_t)W[i];
}

/* ---------------- build WifT ---------------- */
__global__ __launch_bounds__(256) void build_wift(const float* __restrict__ Wi,
                                                  const float* __restrict__ Wf,
                                                  bf16_t* __restrict__ WifT) {
  int idx = blockIdx.x * 256 + threadIdx.x;
  if (idx < 16 * 1536) {
    int n = idx / 1536, k = idx - n * 1536;
    float v = (n < 8) ? Wi[(size_t)k * 8 + n] : Wf[(size_t)k * 8 + (n - 8)];
    WifT[idx] = (bf16_t)v;
  }
}

/* ---------------- LayerNorm ---------------- */
__global__ __launch_bounds__(256) void ln_kernel(const float* __restrict__ x,
                                                 const float* __restrict__ g,
                                                 const float* __restrict__ bta,
                                                 bf16_t* __restrict__ h) {
  size_t tok = blockIdx.x;
  const float* xr = x + tok * Dsz;
  int t = threadIdx.x;
  float v[3]; float s = 0.f;
  #pragma unroll
  for (int i = 0; i < 3; ++i) { v[i] = xr[t + 256 * i]; s += v[i]; }
  s = blockReduceSum256(s);
  float mu = s * (1.f / Dsz);
  float s2 = 0.f;
  #pragma unroll
  for (int i = 0; i < 3; ++i) { float d = v[i] - mu; s2 += d * d; }
  s2 = blockReduceSum256(s2);
  float rs = rsqrtf(s2 * (1.f / Dsz) + 1e-5f);
  #pragma unroll
  for (int i = 0; i < 3; ++i) {
    int col = t + 256 * i;
    h[tok * Dsz + col] = (bf16_t)((v[i] - mu) * rs * g[col] + bta[col]);
  }
}

/* ======================================================================
   256M x 128N m97-style GEMM: C(M,N) = A(M,K) @ Bt(N,K)^T
   512 threads = 8 waves (4M x 2N); BK=64; single-buffer 48 KiB LDS.
   __launch_bounds__(512,4): 2 blocks/CU, VGPR budget fits the 64-reg
   f32x4 accumulator (R8 lesson: (512,6) forced a spill -> 1.5 GB scratch
   traffic, 6x regression).
   128B-row XOR swizzle: byte ^= (row&7)<<4, pre-swizzled global source.
   EPI: 0 = bf16 out; 3 = f32 out + resid; 4 = qkvo (col>=1536: sigmoid).
   ====================================================================== */
template<int EPI>
__global__ __launch_bounds__(512, 4) void gemm_mn(const bf16_t* __restrict__ A,
                                                  const bf16_t* __restrict__ Bt,
                                                  void* __restrict__ Cout,
                                                  const void* __restrict__ extra,
                                                  int M, int N, int K) {
  __shared__ bf16_t As[256 * 64];
  __shared__ bf16_t Bs[128 * 64];
  const int t = threadIdx.x;
  const int w = t >> 6, l = t & 63;
  const int wm = w >> 1, wn = w & 1;
  const int l15 = l & 15, l4 = l >> 4;

  /* bijective XCD swizzle (nwg % 8 == 0 for all launches) */
  const int gx = gridDim.x;
  const int nwg = gx * gridDim.y;
  const int cpx = nwg >> 3;
  int bid = blockIdx.y * gx + blockIdx.x;
  int wg = (bid & 7) * cpx + (bid >> 3);
  const int tile_m = (wg / gx) * 256;
  const int tile_n = (wg % gx) * 128;

  f32x4 acc[4][4];
  #pragma unroll
  for (int m = 0; m < 4; ++m)
    #pragma unroll
    for (int n = 0; n < 4; ++n) acc[m][n] = (f32x4){0.f, 0.f, 0.f, 0.f};

  for (int k0 = 0; k0 < K; k0 += 64) {
    #pragma unroll
    for (int j = 0; j < 4; ++j) {
      int c = t + j * 512;
      int row = c >> 3;
      int ec = ((c & 7) * 8) ^ ((row & 7) << 3);
      gload16(A + (size_t)(tile_m + row) * K + k0 + ec, (char*)As + (size_t)c * 16);
    }
    #pragma unroll
    for (int j = 0; j < 2; ++j) {
      int c = t + j * 512;
      int row = c >> 3;
      int ec = ((c & 7) * 8) ^ ((row & 7) << 3);
      gload16(Bt + (size_t)(tile_n + row) * K + k0 + ec, (char*)Bs + (size_t)c * 16);
    }
    __syncthreads();
    #pragma unroll
    for (int kk = 0; kk < 2; ++kk) {
      bf16x8 aF[4], bF[4];
      #pragma unroll
      for (int m = 0; m < 4; ++m) {
        int r = wm * 64 + m * 16 + l15;
        aF[m] = *(const bf16x8*)((const char*)As + r * 128 + ((kk * 64 + l4 * 16) ^ ((r & 7) << 4)));
      }
      #pragma unroll
      for (int n = 0; n < 4; ++n) {
        int r = wn * 64 + n * 16 + l15;
        bF[n] = *(const bf16x8*)((const char*)Bs + r * 128 + ((kk * 64 + l4 * 16) ^ ((r & 7) << 4)));
      }
      #pragma unroll
      for (int m = 0; m < 4; ++m)
        #pragma unroll
        for (int n = 0; n < 4; ++n)
          acc[m][n] = __builtin_amdgcn_mfma_f32_16x16x32_bf16(aF[m], bF[n], acc[m][n], 0, 0, 0);
    }
    __syncthreads();
  }

  const int rbase = tile_m + wm * 64 + l4 * 4;
  const int cbase = tile_n + wn * 64 + l15;
  #pragma unroll
  for (int m = 0; m < 4; ++m)
    #pragma unroll
    for (int n = 0; n < 4; ++n)
      #pragma unroll
      for (int j = 0; j < 4; ++j) {
        int row = rbase + m * 16 + j;
        int col = cbase + n * 16;
        float v = acc[m][n][j];
        if constexpr (EPI == 0) {
          ((bf16_t*)Cout)[(size_t)row * N + col] = (bf16_t)v;
        } else if constexpr (EPI == 3) {
          ((float*)Cout)[(size_t)row * N + col] =
              v + ((const float*)extra)[(size_t)row * N + col];
        } else {  /* EPI == 4 */
          if (col < 1536) {
            ((bf16_t*)Cout)[(size_t)row * N + col] = (bf16_t)v;
          } else {
            float z = v + ((const float*)extra)[col - 1536];
            ((bf16_t*)Cout)[(size_t)row * N + col] = (bf16_t)(1.f / (1.f + __expf(-z)));
          }
        }
      }
}

/* ---------------- 128^2 MFMA GEMM (W_oc precompute): EPI 0 bf16 out ---------------- */
template<int EPI>
__global__ __launch_bounds__(256) void gemm_bt(const bf16_t* __restrict__ A,
                                               const bf16_t* __restrict__ Bt,
                                               void* __restrict__ Cout,
                                               const void* __restrict__ extra,
                                               int M, int N, int K) {
  __shared__ bf16_t As[128 * 64];
  __shared__ bf16_t Bs[128 * 64];
  const int t = threadIdx.x;
  const int w = t >> 6, l = t & 63;
  const int tile_m = blockIdx.y * 128, tile_n = blockIdx.x * 128;
  const int wr = w >> 1, wc = w & 1;
  const int lrow = l >> 3;
  const int lks = ((l & 7) * 8) ^ (lrow << 3);
  const int l15 = l & 15, l4 = l >> 4;

  f32x4 acc[4][4];
  #pragma unroll
  for (int m = 0; m < 4; ++m)
    #pragma unroll
    for (int n = 0; n < 4; ++n) acc[m][n] = (f32x4){0.f, 0.f, 0.f, 0.f};

  for (int k0 = 0; k0 < K; k0 += 64) {
    #pragma unroll
    for (int i = 0; i < 4; ++i) {
      int ch = w * 4 + i;
      int row = ch * 8 + lrow;
      gload16(A  + (size_t)(tile_m + row) * K + k0 + lks, &As[ch * 512]);
      gload16(Bt + (size_t)(tile_n + row) * K + k0 + lks, &Bs[ch * 512]);
    }
    __syncthreads();
    #pragma unroll
    for (int kk = 0; kk < 2; ++kk) {
      bf16x8 af[4], bfr[4];
      #pragma unroll
      for (int m = 0; m < 4; ++m) {
        int r = wr * 64 + m * 16 + l15;
        af[m] = *(const bf16x8*)&As[r * 64 + ((kk * 32 + l4 * 8) ^ ((r & 7) << 3))];
      }
      #pragma unroll
      for (int n = 0; n < 4; ++n) {
        int r = wc * 64 + n * 16 + l15;
        bfr[n] = *(const bf16x8*)&Bs[r * 64 + ((kk * 32 + l4 * 8) ^ ((r & 7) << 3))];
      }
      #pragma unroll
      for (int m = 0; m < 4; ++m)
        #pragma unroll
        for (int n = 0; n < 4; ++n)
          acc[m][n] = __builtin_amdgcn_mfma_f32_16x16x32_bf16(af[m], bfr[n], acc[m][n], 0, 0, 0);
    }
    __syncthreads();
  }

  const int rbase = tile_m + wr * 64 + l4 * 4;
  const int cbase = tile_n + wc * 64 + l15;
  #pragma unroll
  for (int m = 0; m < 4; ++m)
    #pragma unroll
    for (int n = 0; n < 4; ++n)
      #pragma unroll
      for (int j = 0; j < 4; ++j) {
        int row = rbase + m * 16 + j;
        int col = cbase + n * 16;
        float v = acc[m][n][j];
        if constexpr (EPI == 0) {
          ((bf16_t*)Cout)[(size_t)row * N + col] = (bf16_t)v;
        } else {
          ((float*)Cout)[(size_t)row * N + col] =
              v + ((const float*)extra)[(size_t)row * N + col];
        }
      }
}

/* ---------------- i/f gate projection MFMA GEMM: M=8192 N=16 K=1536 ---------------- */
__global__ __launch_bounds__(256) void ifproj_mfma(const bf16_t* __restrict__ u,
                                                   const bf16_t* __restrict__ WifT,
                                                   const float* __restrict__ bi,
                                                   const float* __restrict__ bfv,
                                                   float* __restrict__ ifb) {
  __shared__ bf16_t As[128 * 64];
  __shared__ bf16_t Bs[16 * 64];
  const int t = threadIdx.x, w = t >> 6, l = t & 63;
  const int l15 = l & 15, l4 = l >> 4;
  const int lrow = l >> 3, lk = (l & 7) * 8;
  const int tile_m = blockIdx.x * 128;
  f32x4 acc[2];
  acc[0] = (f32x4){0.f, 0.f, 0.f, 0.f};
  acc[1] = (f32x4){0.f, 0.f, 0.f, 0.f};

  for (int k0 = 0; k0 < Isz; k0 += 64) {
    #pragma unroll
    for (int i = 0; i < 4; ++i) {
      int ch = w * 4 + i;
      int row = ch * 8 + lrow;
      gload16(u + (size_t)(tile_m + row) * Isz + k0 + lk, &As[ch * 512]);
    }
    if (t < 128) {
      int rr = t >> 3, c0 = (t & 7) * 8;
      *(bf16x8*)&Bs[rr * 64 + c0] = *(const bf16x8*)(WifT + (size_t)rr * Isz + k0 + c0);
    }
    __syncthreads();
    #pragma unroll
    for (int kk = 0; kk < 2; ++kk) {
      bf16x8 bfr = *(const bf16x8*)&Bs[l15 * 64 + kk * 32 + l4 * 8];
      #pragma unroll
      for (int m = 0; m < 2; ++m) {
        bf16x8 af = *(const bf16x8*)&As[(w * 32 + m * 16 + l15) * 64 + kk * 32 + l4 * 8];
        acc[m] = __builtin_amdgcn_mfma_f32_16x16x32_bf16(af, bfr, acc[m], 0, 0, 0);
      }
    }
    __syncthreads();
  }
  float bias = (l15 < 8) ? bi[l15] : bfv[l15 - 8];
  #pragma unroll
  for (int m = 0; m < 2; ++m)
    #pragma unroll
    for (int j = 0; j < 4; ++j) {
      int row = tile_m + w * 32 + m * 16 + l4 * 4 + j;
      ifb[(size_t)row * 16 + l15] = acc[m][j] + bias;
    }
}

/* ---------------- gates pass A ---------------- */
__global__ __launch_bounds__(64) void gates_a(const float* __restrict__ ifb,
                                              float* __restrict__ blocal,
                                              float* __restrict__ Mhat) {
  int bh = blockIdx.x >> 5, c = blockIdx.x & 31;
  int b = bh >> 3, h = bh & 7;
  int lane = threadIdx.x;
  size_t tok = (size_t)b * Ssz + c * Lc + lane;
  float iv = ifb[tok * 16 + h];
  float fv = ifb[tok * 16 + 8 + h];
  float bt = fv;
  #pragma unroll
  for (int d = 1; d < 64; d <<= 1) { float o = __shfl_up(bt, d, 64); if (lane >= d) bt += o; }
  float a = iv - bt;
  float pm = a;
  #pragma unroll
  for (int d = 1; d < 64; d <<= 1) { float o = __shfl_up(pm, d, 64); if (lane >= d) pm = fmaxf(pm, o); }
  blocal[(size_t)bh * Ssz + c * Lc + lane] = bt;
  Mhat[(size_t)bh * Ssz + c * Lc + lane] = bt + pm;
}

/* ---------------- gates pass B ---------------- */
__global__ void gates_b(const float* __restrict__ blocal, const float* __restrict__ Mhat,
                        float* __restrict__ mstart, float* __restrict__ decays,
                        float* __restrict__ mend) {
  int bh = threadIdx.x;
  if (bh < NBH) {
    float M = 0.f;
    for (int c = 0; c < NCH; ++c) {
      mstart[bh * NCH + c] = M;
      float bL = blocal[(size_t)bh * Ssz + c * Lc + 63];
      float Mh = Mhat[(size_t)bh * Ssz + c * Lc + 63];
      float Mn = fmaxf(M + bL, Mh);
      decays[bh * NCH + c] = __expf(M + bL - Mn);
      mend[bh * NCH + c] = Mn;
      M = Mn;
    }
  }
}

/* ---------------- k/v transpose ---------------- */
__global__ __launch_bounds__(256) void kv_transpose(const bf16_t* __restrict__ qkvo,
                                                    bf16_t* __restrict__ kTg,
                                                    bf16_t* __restrict__ vTg) {
  int bh = blockIdx.x >> 5, st = blockIdx.x & 31;
  int b = bh >> 3, h = bh & 7;
  __shared__ bf16_t Lk[64 * 72];
  __shared__ bf16_t Lv[64 * 72];
  int t = threadIdx.x;
  size_t tok0 = (size_t)b * Ssz + st * 64;
  #pragma unroll
  for (int i = 0; i < 2; ++i) {
    int e = t + i * 256; int r = e >> 3, c0 = (e & 7) * 8;
    bf16x8 kv = *(const bf16x8*)(qkvo + (tok0 + r) * 2048 + 512 + h * 64 + c0);
    bf16x8 vv = *(const bf16x8*)(qkvo + (tok0 + r) * 2048 + 1024 + h * 64 + c0);
    *(bf16x8*)&Lk[r * 72 + c0] = kv;
    *(bf16x8*)&Lv[r * 72 + c0] = vv;
  }
  __syncthreads();
  #pragma unroll
  for (int i = 0; i < 2; ++i) {
    int e = t + i * 256; int d = e >> 3, s0 = (e & 7) * 8;
    bf16x8 ok, ov;
    #pragma unroll
    for (int j = 0; j < 8; ++j) {
      ok[j] = Lk[(s0 + j) * 72 + d];
      ov[j] = Lv[(s0 + j) * 72 + d];
    }
    *(bf16x8*)(kTg + ((size_t)bh * 64 + d) * Ssz + st * 64 + s0) = ok;
    *(bf16x8*)(vTg + ((size_t)bh * 64 + d) * Ssz + st * 64 + s0) = ov;
  }
}

/* ---------------- per-chunk state increment, MFMA ---------------- */
__global__ __launch_bounds__(256) void chunk_inc_mfma(const bf16_t* __restrict__ kTg,
                                                      const bf16_t* __restrict__ vTg,
                                                      const float* __restrict__ ifb,
                                                      const float* __restrict__ blocal,
                                                      const float* __restrict__ mend,
                                                      bf16_t* __restrict__ G,
                                                      float* __restrict__ ng) {
  int bh = blockIdx.x >> 5, c = blockIdx.x & 31;
  int b = bh >> 3, h = bh & 7;
  __shared__ bf16_t Vt[64 * 64];
  __shared__ bf16_t Kw[64 * 64];
  __shared__ float wsh[64];
  const int t = threadIdx.x, w = t >> 6, l = t & 63;
  const int l15 = l & 15, l4 = l >> 4;
  if (t < 64) {
    float mL = mend[bh * NCH + c];
    float bL = blocal[(size_t)bh * Ssz + c * Lc + 63];
    float bt = blocal[(size_t)bh * Ssz + c * Lc + t];
    float iv = ifb[((size_t)b * Ssz + c * Lc + t) * 16 + h];
    wsh[t] = __expf(iv + bL - bt - mL);
  }
  __syncthreads();
  {
    const int r = l >> 3, c8 = (l & 7) * 8;
    #pragma unroll
    for (int i = 0; i < 2; ++i) {
      int seg = w * 2 + i, row = seg * 8 + r;
      gload16(vTg + ((size_t)bh * 64 + row) * Ssz + c * 64 + c8, &Vt[seg * 512]);
    }
    #pragma unroll
    for (int i = 0; i < 2; ++i) {
      int e = t + i * 256; int row = e >> 3, c0 = (e & 7) * 8;
      bf16x8 kv = *(const bf16x8*)(kTg + ((size_t)bh * 64 + row) * Ssz + c * 64 + c0);
      #pragma unroll
      for (int j = 0; j < 8; ++j) kv[j] = (bf16_t)((float)kv[j] * wsh[c0 + j]);
      *(bf16x8*)&Kw[row * 64 + c0] = kv;
    }
  }
  __syncthreads();
  f32x4 acc[4];
  #pragma unroll
  for (int n = 0; n < 4; ++n) acc[n] = (f32x4){0.f, 0.f, 0.f, 0.f};
  #pragma unroll
  for (int kk = 0; kk < 2; ++kk) {
    bf16x8 af = *(const bf16x8*)&Vt[(w * 16 + l15) * 64 + kk * 32 + l4 * 8];
    #pragma unroll
    for (int n = 0; n < 4; ++n) {
      bf16x8 bfr = *(const bf16x8*)&Kw[(n * 16 + l15) * 64 + kk * 32 + l4 * 8];
      acc[n] = __builtin_amdgcn_mfma_f32_16x16x32_bf16(af, bfr, acc[n], 0, 0, 0);
    }
  }
  size_t gb = ((size_t)bh * NCH + c) * 4096;
  #pragma unroll
  for (int n = 0; n < 4; ++n)
    #pragma unroll
    for (int j = 0; j < 4; ++j) {
      int row = w * 16 + l4 * 4 + j;
      int col = n * 16 + l15;
      G[gb + (size_t)row * 64 + col] = (bf16_t)acc[n][j];
    }
  if (t < 64) {
    float s = 0.f;
    for (int s2 = 0; s2 < 64; ++s2) s += (float)Kw[t * 64 + s2];
    ng[((size_t)bh * NCH + c) * 64 + t] = s;
  }
}

/* ---------------- state scan ---------------- */
__global__ __launch_bounds__(256) void state_scan(const bf16_t* __restrict__ G,
                                                  const float* __restrict__ ng,
                                                  const float* __restrict__ decays,
                                                  bf16_t* __restrict__ CstB,
                                                  float* __restrict__ nst) {
  int gid = blockIdx.x;
  if (gid < 512) {
    int idx = gid * 256 + threadIdx.x;
    int bh = idx >> 12, e = idx & 4095;
    const float* d = decays + bh * NCH;
    float C = 0.f;
    #pragma unroll
    for (int c = 0; c < NCH; ++c) {
      size_t o = ((size_t)bh * NCH + c) * 4096 + e;
      CstB[o] = (bf16_t)C;
      C = d[c] * C + (float)G[o];
    }
  } else {
    int idx = (gid - 512) * 256 + threadIdx.x;
    int bh = idx >> 6, e = idx & 63;
    const float* d = decays + bh * NCH;
    float n = 0.f;
    #pragma unroll
    for (int c = 0; c < NCH; ++c) {
      size_t o = ((size_t)bh * NCH + c) * 64 + e;
      nst[o] = n;
      n = d[c] * n + ng[o];
    }
  }
}

/* ---------------- intra-chunk outputs, MFMA ---------------- */
__global__ __launch_bounds__(256) void intra_mfma(const bf16_t* __restrict__ qkvo,
                                                  const bf16_t* __restrict__ vTg,
                                                  const bf16_t* __restrict__ CstB,
                                                  const float* __restrict__ nst,
                                                  const float* __restrict__ ifb,
                                                  const float* __restrict__ blocal,
                                                  const float* __restrict__ Mhat,
                                                  const float* __restrict__ mstart,
                                                  float* __restrict__ ht) {
  int bh = blockIdx.x >> 5, c = blockIdx.x & 31;
  int b = bh >> 3, h = bh & 7;
  __shared__ bf16_t qs[64 * 64];
  __shared__ bf16_t ks[64 * 64];
  __shared__ bf16_t vTs[64 * 64];
  __shared__ bf16_t Cs[64 * 64];
  __shared__ float nin[64], den_s[64], ssrc[64], sdst[64], esc[64];
  const int t = threadIdx.x, w = t >> 6, l = t & 63;
  const int l15 = l & 15, l4 = l >> 4;
  const size_t tok0 = (size_t)b * Ssz + c * Lc;
  const size_t cbase = ((size_t)bh * NCH + c) * 4096;

  if (t < 64) {
    nin[t] = nst[((size_t)bh * NCH + c) * 64 + t];
    float bt = blocal[(size_t)bh * Ssz + c * Lc + t];
    float Mh2 = Mhat[(size_t)bh * Ssz + c * Lc + t];
    float Mc = mstart[bh * NCH + c];
    float iv = ifb[(tok0 + t) * 16 + h];
    float mt = fmaxf(Mc + bt, Mh2);
    ssrc[t] = iv - bt;
    sdst[t] = bt - mt;
    esc[t]  = __expf(Mc + bt - mt);
  }
  {
    const int r = l >> 3, c8 = (l & 7) * 8;
    #pragma unroll
    for (int i = 0; i < 2; ++i) {
      int seg = w * 2 + i, row = seg * 8 + r;
      gload16(qkvo + (tok0 + row) * 2048 + h * 64 + c8,          &qs[seg * 512]);
      gload16(qkvo + (tok0 + row) * 2048 + 512 + h * 64 + c8,    &ks[seg * 512]);
      gload16(vTg + ((size_t)bh * 64 + row) * Ssz + c * 64 + c8, &vTs[seg * 512]);
      gload16(CstB + cbase + seg * 512 + l * 8,                  &Cs[seg * 512]);
    }
  }
  __syncthreads();

  f32x4 aS[4];
  #pragma unroll
  for (int n = 0; n < 4; ++n) aS[n] = (f32x4){0.f, 0.f, 0.f, 0.f};
  #pragma unroll
  for (int kk = 0; kk < 2; ++kk) {
    bf16x8 af = *(const bf16x8*)&qs[(w * 16 + l15) * 64 + kk * 32 + l4 * 8];
    #pragma unroll
    for (int n = 0; n < 4; ++n) {
      bf16x8 bfr = *(const bf16x8*)&ks[(n * 16 + l15) * 64 + kk * 32 + l4 * 8];
      aS[n] = __builtin_amdgcn_mfma_f32_16x16x32_bf16(af, bfr, aS[n], 0, 0, 0);
    }
  }
  {
    int row = w * 16 + (l >> 2);
    int c0 = (l & 3) * 16;
    float e = esc[row];
    #pragma unroll
    for (int i2 = 0; i2 < 2; ++i2) {
      bf16x8 v8 = *(const bf16x8*)&qs[row * 64 + c0 + i2 * 8];
      #pragma unroll
      for (int j = 0; j < 8; ++j) v8[j] = (bf16_t)((float)v8[j] * e);
      *(bf16x8*)&qs[row * 64 + c0 + i2 * 8] = v8;
    }
  }
  float rs[4] = {0.f, 0.f, 0.f, 0.f};
  #pragma unroll
  for (int n = 0; n < 4; ++n) {
    int col = n * 16 + l15;
    float es = ssrc[col];
    #pragma unroll
    for (int j = 0; j < 4; ++j) {
      int row = w * 16 + l4 * 4 + j;
      float p = (col <= row) ? aS[n][j] * __expf(es + sdst[row]) : 0.f;
      aS[n][j] = p;
      rs[j] += p;
    }
  }
  #pragma unroll
  for (int j = 0; j < 4; ++j) {
    rs[j] += __shfl_xor(rs[j], 1, 64);
    rs[j] += __shfl_xor(rs[j], 2, 64);
    rs[j] += __shfl_xor(rs[j], 4, 64);
    rs[j] += __shfl_xor(rs[j], 8, 64);
  }
  if (l15 == 0) {
    #pragma unroll
    for (int j = 0; j < 4; ++j) den_s[w * 16 + l4 * 4 + j] = rs[j];
  }
  __syncthreads();

  #pragma unroll
  for (int n = 0; n < 4; ++n)
    #pragma unroll
    for (int j = 0; j < 4; ++j)
      ks[(w * 16 + l4 * 4 + j) * 64 + n * 16 + l15] = (bf16_t)aS[n][j];

  {
    int row = w * 16 + (l >> 2);
    int c0 = (l & 3) * 16;
    float part = 0.f;
    #pragma unroll
    for (int i2 = 0; i2 < 16; ++i2)
      part += (float)qs[row * 64 + c0 + i2] * nin[c0 + i2];
    part += __shfl_xor(part, 1, 64);
    part += __shfl_xor(part, 2, 64);
    if ((l & 3) == 0)
      den_s[row] = fmaxf(fabsf(den_s[row] + part), 1.0f);
  }
  __syncthreads();

  f32x4 aO[4];
  #pragma unroll
  for (int n = 0; n < 4; ++n) aO[n] = (f32x4){0.f, 0.f, 0.f, 0.f};
  #pragma unroll
  for (int kk = 0; kk < 2; ++kk) {
    bf16x8 afP = *(const bf16x8*)&ks[(w * 16 + l15) * 64 + kk * 32 + l4 * 8];
    bf16x8 afQ = *(const bf16x8*)&qs[(w * 16 + l15) * 64 + kk * 32 + l4 * 8];
    #pragma unroll
    for (int n = 0; n < 4; ++n) {
      bf16x8 bV = *(const bf16x8*)&vTs[(n * 16 + l15) * 64 + kk * 32 + l4 * 8];
      bf16x8 bC = *(const bf16x8*)&Cs[(n * 16 + l15) * 64 + kk * 32 + l4 * 8];
      aO[n] = __builtin_amdgcn_mfma_f32_16x16x32_bf16(afP, bV, aO[n], 0, 0, 0);
      aO[n] = __builtin_amdgcn_mfma_f32_16x16x32_bf16(afQ, bC, aO[n], 0, 0, 0);
    }
  }
  #pragma unroll
  for (int j = 0; j < 4; ++j) {
    int row = w * 16 + l4 * 4 + j;
    float rinv = 1.f / den_s[row];
    size_t rowg = ((tok0 + row) * Hn + h) * HDsz;
    #pragma unroll
    for (int n = 0; n < 4; ++n)
      ht[rowg + n * 16 + l15] = aO[n][j] * rinv;
  }
}

/* ---------------- group-norm + output gate ---------------- */
__global__ __launch_bounds__(256) void gn_gate(const float* __restrict__ ht,
                                               const bf16_t* __restrict__ qkvo,
                                               const float* __restrict__ mhg,
                                               bf16_t* __restrict__ gated) {
  int gid = blockIdx.x * 4 + (threadIdx.x >> 6);
  int lane = threadIdx.x & 63;
  int h = gid & 7;
  size_t tok = (size_t)(gid >> 3);
  size_t idx = (size_t)gid * 64 + lane;
  float v = ht[idx];
  float s = v;
  #pragma unroll
  for (int o = 1; o < 64; o <<= 1) s += __shfl_xor(s, o, 64);
  float mu = s * (1.f / 64.f);
  float d = v - mu;
  float s2 = d * d;
  #pragma unroll
  for (int o = 1; o < 64; o <<= 1) s2 += __shfl_xor(s2, o, 64);
  float hn = d * rsqrtf(s2 * (1.f / 64.f) + 1e-5f) * mhg[h * 64 + lane];
  float og = (float)qkvo[tok * 2048 + 1536 + h * 64 + lane];
  gated[idx] = (bf16_t)(og * hn);
}

/* ---------------- launcher ---------------- */
extern "C" void kernel_launch(void* const* d_in, const int* in_sizes, int n_in,
                              void* d_out, int out_size, void* d_ws, size_t ws_size,
                              hipStream_t stream) {
  const float* x     = (const float*)d_in[0];
  const float* ln_g  = (const float*)d_in[1];
  const float* ln_b  = (const float*)d_in[2];
  const float* W_up  = (const float*)d_in[3];
  const float* W_down= (const float*)d_in[4];
  const float* Wq    = (const float*)d_in[5];
  const float* Wk    = (const float*)d_in[6];
  const float* Wv    = (const float*)d_in[7];
  const float* Wi    = (const float*)d_in[8];
  const float* bi    = (const float*)d_in[9];
  const float* Wf    = (const float*)d_in[10];
  const float* bfv   = (const float*)d_in[11];
  const float* Wo    = (const float*)d_in[12];
  const float* bo    = (const float*)d_in[13];
  const float* mh_g  = (const float*)d_in[14];
  const float* W_out = (const float*)d_in[15];

  char* ws = (char*)d_ws;
  bf16_t* hbuf   = (bf16_t*)(ws + OFF_H);
  bf16_t* wupT   = (bf16_t*)(ws + OFF_WUPT);
  bf16_t* wqkvoT = (bf16_t*)(ws + OFF_WQKVO);
  bf16_t* woutB  = (bf16_t*)(ws + OFF_WOUTB);
  bf16_t* wdownT = (bf16_t*)(ws + OFF_WDOWNT);
  bf16_t* ubuf   = (bf16_t*)(ws + OFF_U);
  bf16_t* qkvob  = (bf16_t*)(ws + OFF_QKVO);
  bf16_t* kTg    = (bf16_t*)(ws + OFF_KT);
  bf16_t* vTg    = (bf16_t*)(ws + OFF_VT);
  float*  ifb    = (float*)(ws + OFF_IFB);
  float*  bloc   = (float*)(ws + OFF_BLOC);
  float*  Mh     = (float*)(ws + OFF_MHAT);
  float*  mst    = (float*)(ws + OFF_MST);
  float*  decays = (float*)(ws + OFF_DEC);
  float*  mendb  = (float*)(ws + OFF_MEND);
  float*  ngbuf  = (float*)(ws + OFF_NG);
  float*  nst    = (float*)(ws + OFF_NST);
  bf16_t* wifT   = (bf16_t*)(ws + OFF_WIFT);
  bf16_t* wocT   = (bf16_t*)(ws + OFF_WOC);
  bf16_t* CstB   = (bf16_t*)(ws + OFF_CSTB);
  float*  htbuf  = (float*)(ws + OFF_HT);
  bf16_t* Gbuf   = (bf16_t*)(ws + OFF_G);
  bf16_t* gbuf   = (bf16_t*)(ws + OFF_GATED);

  dim3 tb(32, 8);
  transpose_cast<<<dim3(Isz / 32, Dsz / 32), tb, 0, stream>>>(W_up, wupT, Dsz, Isz, 1.f);
  transpose_cast<<<dim3(512 / 32, Isz / 32), tb, 0, stream>>>(Wq, wqkvoT,                    Isz, 512, 1.f);
  transpose_cast<<<dim3(512 / 32, Isz / 32), tb, 0, stream>>>(Wk, wqkvoT + (size_t)512*Isz,  Isz, 512, 0.125f);
  transpose_cast<<<dim3(512 / 32, Isz / 32), tb, 0, stream>>>(Wv, wqkvoT + (size_t)1024*Isz, Isz, 512, 1.f);
  transpose_cast<<<dim3(512 / 32, Isz / 32), tb, 0, stream>>>(Wo, wqkvoT + (size_t)1536*Isz, Isz, 512, 1.f);
  transpose_cast<<<dim3(Dsz / 32, Isz / 32), tb, 0, stream>>>(W_down, wdownT, Isz, Dsz, 1.f);
  cast_bf16<<<(512 * 1536 + 255) / 256, 256, 0, stream>>>(W_out, woutB, 512 * 1536);
  build_wift<<<96, 256, 0, stream>>>(Wi, Wf, wifT);

  /* WocT(768,512) = wdownT(768,K=1536) @ woutB(512,K=1536)^T  ==  (W_out @ W_down)^T */
  gemm_bt<0><<<dim3(512 / 128, Dsz / 128), 256, 0, stream>>>(wdownT, woutB, wocT, nullptr, Dsz, 512, Isz);

  ln_kernel<<<NTOK, 256, 0, stream>>>(x, ln_g, ln_b, hbuf);

  gemm_mn<0><<<dim3(Isz / 128, NTOK / 256), 512, 0, stream>>>(hbuf, wupT, ubuf, nullptr, NTOK, Isz, Dsz);
  gemm_mn<4><<<dim3(2048 / 128, NTOK / 256), 512, 0, stream>>>(ubuf, wqkvoT, qkvob, bo, NTOK, 2048, Isz);

  ifproj_mfma<<<NTOK / 128, 256, 0, stream>>>(ubuf, wifT, bi, bfv, ifb);
  kv_transpose<<<NBH * NCH, 256, 0, stream>>>(qkvob, kTg, vTg);

  gates_a<<<NBH * NCH, 64, 0, stream>>>(ifb, bloc, Mh);
  gates_b<<<1, 32, 0, stream>>>(bloc, Mh, mst, decays, mendb);
  chunk_inc_mfma<<<NBH * NCH, 256, 0, stream>>>(kTg, vTg, ifb, bloc, mendb, Gbuf, ngbuf);
  state_scan<<<520, 256, 0, stream>>>(Gbuf, ngbuf, decays, CstB, nst);
  intra_mfma<<<NBH * NCH, 256, 0, stream>>>(qkvob, vTg, CstB, nst, ifb, bloc, Mh, mst, htbuf);

  gn_gate<<<NTOK * Hn / 4, 256, 0, stream>>>(htbuf, qkvob, mh_g, gbuf);
  /* fused: out = x + gated @ (W_out @ W_down), K=512 */
  gemm_mn<3><<<dim3(Dsz / 128, NTOK / 256), 512, 0, stream>>>(gbuf, wocT, (float*)d_out, x, NTOK, Dsz, 512);
}

// Round 10
// 226.524 us; speedup vs baseline: 3.0949x; 1.0365x over previous
//
#include <hip/hip_runtime.h>
#include <hip/hip_bf16.h>
#include <stdint.h>
#include <stddef.h>

typedef __bf16 bf16_t;
typedef __bf16 bf16x4 __attribute__((ext_vector_type(4)));
typedef __bf16 bf16x8 __attribute__((ext_vector_type(8)));
typedef float  f32x4  __attribute__((ext_vector_type(4)));

#define Bsz  4
#define Ssz  2048
#define Dsz  768
#define Isz  1536
#define Hn   8
#define HDsz 64
#define NTOK (Bsz*Ssz)      /* 8192 */
#define Lc   64
#define NCH  (Ssz/Lc)       /* 32 */
#define NBH  (Bsz*Hn)       /* 32 */
#define NQX  2176           /* qkvo+if fused N (17 tiles of 128) */

/* ---------------- workspace layout (bytes) ---------------- */
#define OFF_H      ((size_t)0)                    /* 12.58M; CstB aliases 0 */
#define OFF_WUPT   ((size_t)12582912)             /* 2.36M */
#define OFF_WQX    ((size_t)14942208)             /* 2176x1536 bf16 = 6.68M */
#define OFF_WDOWNT ((size_t)21626880)             /* 2.36M */
#define OFF_WOC    ((size_t)23986176)             /* 768x512 bf16 = 0.79M */
#define OFF_BIAS   ((size_t)24772608)             /* 528 f32 (pad 4K) */
#define OFF_U      ((size_t)24776704)             /* 25.17M */
#define OFF_QKVO   ((size_t)49942528)             /* 8192x2048 bf16 = 33.55M */
#define OFF_KT     ((size_t)83496960)             /* 8.39M */
#define OFF_VT     ((size_t)91885568)             /* 8.39M */
#define OFF_IFB    ((size_t)100274176)            /* 0.52M */
#define OFF_BLOC   ((size_t)100798464)
#define OFF_MHAT   ((size_t)101060608)
#define OFF_MST    ((size_t)101322752)
#define OFF_DEC    ((size_t)101326848)
#define OFF_MEND   ((size_t)101330944)
#define OFF_NG     ((size_t)101335040)
#define OFF_NST    ((size_t)101597184)            /* end 101859328 */
/* aliases */
#define OFF_CSTB   ((size_t)0)                    /* over H (dead after up-gemm) */
#define OFF_WOUTB  OFF_QKVO                       /* W_out bf16, dead before qkvo write */
#define OFF_G      OFF_U                          /* over u (dead after qkvo-gemm) */
#define OFF_GATED  (OFF_U + 16777216)

/* ---------------- helpers ---------------- */
__device__ __forceinline__ void gload16(const void* gsrc, void* ldst) {
  __builtin_amdgcn_global_load_lds(
      (const __attribute__((address_space(1))) void*)gsrc,
      (__attribute__((address_space(3))) void*)ldst, 16, 0, 0);
}

__device__ __forceinline__ float blockReduceSum256(float v) {
  #pragma unroll
  for (int o = 1; o < 64; o <<= 1) v += __shfl_xor(v, o, 64);
  __shared__ float sh[4];
  int wid = threadIdx.x >> 6;
  __syncthreads();
  if ((threadIdx.x & 63) == 0) sh[wid] = v;
  __syncthreads();
  return sh[0] + sh[1] + sh[2] + sh[3];
}

/* ---------------- weight transpose+cast ---------------- */
__global__ __launch_bounds__(256) void transpose_cast(const float* __restrict__ W,
                                                      bf16_t* __restrict__ Wt,
                                                      int K, int N, float scale) {
  __shared__ float tile[32][33];
  int n0 = blockIdx.x * 32, k0 = blockIdx.y * 32;
  int tx = threadIdx.x, ty = threadIdx.y;
  #pragma unroll
  for (int j = 0; j < 32; j += 8)
    tile[ty + j][tx] = W[(size_t)(k0 + ty + j) * N + n0 + tx];
  __syncthreads();
  #pragma unroll
  for (int j = 0; j < 32; j += 8)
    Wt[(size_t)(n0 + ty + j) * K + k0 + tx] = (bf16_t)(tile[tx][ty + j] * scale);
}

/* ---------------- plain f32 -> bf16 cast ---------------- */
__global__ __launch_bounds__(256) void cast_bf16(const float* __restrict__ W,
                                                 bf16_t* __restrict__ Wb, int n) {
  int i = blockIdx.x * 256 + threadIdx.x;
  if (i < n) Wb[i] = (bf16_t)W[i];
}

/* ---------------- build Wif^T into wqx rows 2048-2063 ---------------- */
__global__ __launch_bounds__(256) void build_wift(const float* __restrict__ Wi,
                                                  const float* __restrict__ Wf,
                                                  bf16_t* __restrict__ dst) {
  int idx = blockIdx.x * 256 + threadIdx.x;
  if (idx < 16 * 1536) {
    int n = idx / 1536, k = idx - n * 1536;
    float v = (n < 8) ? Wi[(size_t)k * 8 + n] : Wf[(size_t)k * 8 + (n - 8)];
    dst[idx] = (bf16_t)v;
  }
}

/* ---------------- packed bias [bo(512), bi(8), bf(8)] ---------------- */
__global__ void build_bias(const float* __restrict__ bo, const float* __restrict__ bi,
                           const float* __restrict__ bfv, float* __restrict__ out) {
  int i = blockIdx.x * 256 + threadIdx.x;
  if (i < 512) out[i] = bo[i];
  else if (i < 520) out[i] = bi[i - 512];
  else if (i < 528) out[i] = bfv[i - 520];
}

/* ---------------- LayerNorm ---------------- */
__global__ __launch_bounds__(256) void ln_kernel(const float* __restrict__ x,
                                                 const float* __restrict__ g,
                                                 const float* __restrict__ bta,
                                                 bf16_t* __restrict__ h) {
  size_t tok = blockIdx.x;
  const float* xr = x + tok * Dsz;
  int t = threadIdx.x;
  float v[3]; float s = 0.f;
  #pragma unroll
  for (int i = 0; i < 3; ++i) { v[i] = xr[t + 256 * i]; s += v[i]; }
  s = blockReduceSum256(s);
  float mu = s * (1.f / Dsz);
  float s2 = 0.f;
  #pragma unroll
  for (int i = 0; i < 3; ++i) { float d = v[i] - mu; s2 += d * d; }
  s2 = blockReduceSum256(s2);
  float rs = rsqrtf(s2 * (1.f / Dsz) + 1e-5f);
  #pragma unroll
  for (int i = 0; i < 3; ++i) {
    int col = t + 256 * i;
    h[tok * Dsz + col] = (bf16_t)((v[i] - mu) * rs * g[col] + bta[col]);
  }
}

/* ======================================================================
   256M x 128N m97-style GEMM (proven config: launch_bounds(512,4), VGPR 60).
   EPI: 0 = bf16 out; 3 = f32 out + resid;
        5 = fused qkvo/if epilogue (N must be NQX=2176, Cout stride 2048):
            col<512   q  -> qkvo
            col<1024  k  -> qkvo + kTg (transposed, bf16x4 per 4 rows)
            col<1536  v  -> vTg only
            col<2048  o  -> qkvo = sigmoid(acc + bias[col-1536])
            col<2064  if -> ifb f32 = acc + bias[col-1536]
            else discard (weight rows zeroed)
   ====================================================================== */
template<int EPI>
__global__ __launch_bounds__(512, 4) void gemm_mn(const bf16_t* __restrict__ A,
                                                  const bf16_t* __restrict__ Bt,
                                                  void* __restrict__ Cout,
                                                  const void* __restrict__ extra,
                                                  bf16_t* __restrict__ kTg,
                                                  bf16_t* __restrict__ vTg,
                                                  float* __restrict__ ifb,
                                                  int M, int N, int K) {
  __shared__ bf16_t As[256 * 64];
  __shared__ bf16_t Bs[128 * 64];
  const int t = threadIdx.x;
  const int w = t >> 6, l = t & 63;
  const int wm = w >> 1, wn = w & 1;
  const int l15 = l & 15, l4 = l >> 4;

  /* bijective XCD swizzle (nwg % 8 == 0 for all launches) */
  const int gx = gridDim.x;
  const int nwg = gx * gridDim.y;
  const int cpx = nwg >> 3;
  int bid = blockIdx.y * gx + blockIdx.x;
  int wg = (bid & 7) * cpx + (bid >> 3);
  const int tile_m = (wg / gx) * 256;
  const int tile_n = (wg % gx) * 128;

  f32x4 acc[4][4];
  #pragma unroll
  for (int m = 0; m < 4; ++m)
    #pragma unroll
    for (int n = 0; n < 4; ++n) acc[m][n] = (f32x4){0.f, 0.f, 0.f, 0.f};

  for (int k0 = 0; k0 < K; k0 += 64) {
    #pragma unroll
    for (int j = 0; j < 4; ++j) {
      int c = t + j * 512;
      int row = c >> 3;
      int ec = ((c & 7) * 8) ^ ((row & 7) << 3);
      gload16(A + (size_t)(tile_m + row) * K + k0 + ec, (char*)As + (size_t)c * 16);
    }
    #pragma unroll
    for (int j = 0; j < 2; ++j) {
      int c = t + j * 512;
      int row = c >> 3;
      int ec = ((c & 7) * 8) ^ ((row & 7) << 3);
      gload16(Bt + (size_t)(tile_n + row) * K + k0 + ec, (char*)Bs + (size_t)c * 16);
    }
    __syncthreads();
    #pragma unroll
    for (int kk = 0; kk < 2; ++kk) {
      bf16x8 aF[4], bF[4];
      #pragma unroll
      for (int m = 0; m < 4; ++m) {
        int r = wm * 64 + m * 16 + l15;
        aF[m] = *(const bf16x8*)((const char*)As + r * 128 + ((kk * 64 + l4 * 16) ^ ((r & 7) << 4)));
      }
      #pragma unroll
      for (int n = 0; n < 4; ++n) {
        int r = wn * 64 + n * 16 + l15;
        bF[n] = *(const bf16x8*)((const char*)Bs + r * 128 + ((kk * 64 + l4 * 16) ^ ((r & 7) << 4)));
      }
      #pragma unroll
      for (int m = 0; m < 4; ++m)
        #pragma unroll
        for (int n = 0; n < 4; ++n)
          acc[m][n] = __builtin_amdgcn_mfma_f32_16x16x32_bf16(aF[m], bF[n], acc[m][n], 0, 0, 0);
    }
    __syncthreads();
  }

  const int rbase = tile_m + wm * 64 + l4 * 4;
  const int cbase = tile_n + wn * 64 + l15;
  if constexpr (EPI == 5) {
    const float* bias = (const float*)extra;
    #pragma unroll
    for (int m = 0; m < 4; ++m) {
      int row0 = rbase + m * 16;             /* rows row0..row0+3, mult of 4 */
      int bb = row0 >> 11, s0 = row0 & 2047;
      #pragma unroll
      for (int n = 0; n < 4; ++n) {
        int col = cbase + n * 16;
        if (col < 512) {
          #pragma unroll
          for (int j = 0; j < 4; ++j)
            ((bf16_t*)Cout)[(size_t)(row0 + j) * 2048 + col] = (bf16_t)acc[m][n][j];
        } else if (col < 1024) {
          int hd = col - 512;
          bf16x4 pk;
          #pragma unroll
          for (int j = 0; j < 4; ++j) {
            bf16_t bv = (bf16_t)acc[m][n][j];
            ((bf16_t*)Cout)[(size_t)(row0 + j) * 2048 + col] = bv;
            pk[j] = bv;
          }
          *(bf16x4*)(kTg + ((size_t)(bb * 8 + (hd >> 6)) * 64 + (hd & 63)) * Ssz + s0) = pk;
        } else if (col < 1536) {
          int hd = col - 1024;
          bf16x4 pv;
          #pragma unroll
          for (int j = 0; j < 4; ++j) pv[j] = (bf16_t)acc[m][n][j];
          *(bf16x4*)(vTg + ((size_t)(bb * 8 + (hd >> 6)) * 64 + (hd & 63)) * Ssz + s0) = pv;
        } else if (col < 2048) {
          float b = bias[col - 1536];
          #pragma unroll
          for (int j = 0; j < 4; ++j) {
            float z = acc[m][n][j] + b;
            ((bf16_t*)Cout)[(size_t)(row0 + j) * 2048 + col] = (bf16_t)(1.f / (1.f + __expf(-z)));
          }
        } else if (col < 2064) {
          float b = bias[col - 1536];
          #pragma unroll
          for (int j = 0; j < 4; ++j)
            ifb[(size_t)(row0 + j) * 16 + (col - 2048)] = acc[m][n][j] + b;
        }
      }
    }
  } else {
    #pragma unroll
    for (int m = 0; m < 4; ++m)
      #pragma unroll
      for (int n = 0; n < 4; ++n)
        #pragma unroll
        for (int j = 0; j < 4; ++j) {
          int row = rbase + m * 16 + j;
          int col = cbase + n * 16;
          float v = acc[m][n][j];
          if constexpr (EPI == 0) {
            ((bf16_t*)Cout)[(size_t)row * N + col] = (bf16_t)v;
          } else {  /* EPI == 3 */
            ((float*)Cout)[(size_t)row * N + col] =
                v + ((const float*)extra)[(size_t)row * N + col];
          }
        }
  }
}

/* ---------------- 128^2 MFMA GEMM (W_oc precompute only) ---------------- */
__global__ __launch_bounds__(256) void gemm_bt(const bf16_t* __restrict__ A,
                                               const bf16_t* __restrict__ Bt,
                                               bf16_t* __restrict__ Cout,
                                               int M, int N, int K) {
  __shared__ bf16_t As[128 * 64];
  __shared__ bf16_t Bs[128 * 64];
  const int t = threadIdx.x;
  const int w = t >> 6, l = t & 63;
  const int tile_m = blockIdx.y * 128, tile_n = blockIdx.x * 128;
  const int wr = w >> 1, wc = w & 1;
  const int lrow = l >> 3;
  const int lks = ((l & 7) * 8) ^ (lrow << 3);
  const int l15 = l & 15, l4 = l >> 4;

  f32x4 acc[4][4];
  #pragma unroll
  for (int m = 0; m < 4; ++m)
    #pragma unroll
    for (int n = 0; n < 4; ++n) acc[m][n] = (f32x4){0.f, 0.f, 0.f, 0.f};

  for (int k0 = 0; k0 < K; k0 += 64) {
    #pragma unroll
    for (int i = 0; i < 4; ++i) {
      int ch = w * 4 + i;
      int row = ch * 8 + lrow;
      gload16(A  + (size_t)(tile_m + row) * K + k0 + lks, &As[ch * 512]);
      gload16(Bt + (size_t)(tile_n + row) * K + k0 + lks, &Bs[ch * 512]);
    }
    __syncthreads();
    #pragma unroll
    for (int kk = 0; kk < 2; ++kk) {
      bf16x8 af[4], bfr[4];
      #pragma unroll
      for (int m = 0; m < 4; ++m) {
        int r = wr * 64 + m * 16 + l15;
        af[m] = *(const bf16x8*)&As[r * 64 + ((kk * 32 + l4 * 8) ^ ((r & 7) << 3))];
      }
      #pragma unroll
      for (int n = 0; n < 4; ++n) {
        int r = wc * 64 + n * 16 + l15;
        bfr[n] = *(const bf16x8*)&Bs[r * 64 + ((kk * 32 + l4 * 8) ^ ((r & 7) << 3))];
      }
      #pragma unroll
      for (int m = 0; m < 4; ++m)
        #pragma unroll
        for (int n = 0; n < 4; ++n)
          acc[m][n] = __builtin_amdgcn_mfma_f32_16x16x32_bf16(af[m], bfr[n], acc[m][n], 0, 0, 0);
    }
    __syncthreads();
  }

  const int rbase = tile_m + wr * 64 + l4 * 4;
  const int cbase = tile_n + wc * 64 + l15;
  #pragma unroll
  for (int m = 0; m < 4; ++m)
    #pragma unroll
    for (int n = 0; n < 4; ++n)
      #pragma unroll
      for (int j = 0; j < 4; ++j)
        Cout[(size_t)(rbase + m * 16 + j) * N + cbase + n * 16] = (bf16_t)acc[m][n][j];
}

/* ---------------- gates pass A ---------------- */
__global__ __launch_bounds__(64) void gates_a(const float* __restrict__ ifb,
                                              float* __restrict__ blocal,
                                              float* __restrict__ Mhat) {
  int bh = blockIdx.x >> 5, c = blockIdx.x & 31;
  int b = bh >> 3, h = bh & 7;
  int lane = threadIdx.x;
  size_t tok = (size_t)b * Ssz + c * Lc + lane;
  float iv = ifb[tok * 16 + h];
  float fv = ifb[tok * 16 + 8 + h];
  float bt = fv;
  #pragma unroll
  for (int d = 1; d < 64; d <<= 1) { float o = __shfl_up(bt, d, 64); if (lane >= d) bt += o; }
  float a = iv - bt;
  float pm = a;
  #pragma unroll
  for (int d = 1; d < 64; d <<= 1) { float o = __shfl_up(pm, d, 64); if (lane >= d) pm = fmaxf(pm, o); }
  blocal[(size_t)bh * Ssz + c * Lc + lane] = bt;
  Mhat[(size_t)bh * Ssz + c * Lc + lane] = bt + pm;
}

/* ---------------- gates pass B ---------------- */
__global__ void gates_b(const float* __restrict__ blocal, const float* __restrict__ Mhat,
                        float* __restrict__ mstart, float* __restrict__ decays,
                        float* __restrict__ mend) {
  int bh = threadIdx.x;
  if (bh < NBH) {
    float M = 0.f;
    for (int c = 0; c < NCH; ++c) {
      mstart[bh * NCH + c] = M;
      float bL = blocal[(size_t)bh * Ssz + c * Lc + 63];
      float Mh = Mhat[(size_t)bh * Ssz + c * Lc + 63];
      float Mn = fmaxf(M + bL, Mh);
      decays[bh * NCH + c] = __expf(M + bL - Mn);
      mend[bh * NCH + c] = Mn;
      M = Mn;
    }
  }
}

/* ---------------- per-chunk state increment, MFMA ---------------- */
__global__ __launch_bounds__(256) void chunk_inc_mfma(const bf16_t* __restrict__ kTg,
                                                      const bf16_t* __restrict__ vTg,
                                                      const float* __restrict__ ifb,
                                                      const float* __restrict__ blocal,
                                                      const float* __restrict__ mend,
                                                      bf16_t* __restrict__ G,
                                                      float* __restrict__ ng) {
  int bh = blockIdx.x >> 5, c = blockIdx.x & 31;
  int b = bh >> 3, h = bh & 7;
  __shared__ bf16_t Vt[64 * 64];
  __shared__ bf16_t Kw[64 * 64];
  __shared__ float wsh[64];
  const int t = threadIdx.x, w = t >> 6, l = t & 63;
  const int l15 = l & 15, l4 = l >> 4;
  if (t < 64) {
    float mL = mend[bh * NCH + c];
    float bL = blocal[(size_t)bh * Ssz + c * Lc + 63];
    float bt = blocal[(size_t)bh * Ssz + c * Lc + t];
    float iv = ifb[((size_t)b * Ssz + c * Lc + t) * 16 + h];
    wsh[t] = __expf(iv + bL - bt - mL);
  }
  __syncthreads();
  {
    const int r = l >> 3, c8 = (l & 7) * 8;
    #pragma unroll
    for (int i = 0; i < 2; ++i) {
      int seg = w * 2 + i, row = seg * 8 + r;
      gload16(vTg + ((size_t)bh * 64 + row) * Ssz + c * 64 + c8, &Vt[seg * 512]);
    }
    #pragma unroll
    for (int i = 0; i < 2; ++i) {
      int e = t + i * 256; int row = e >> 3, c0 = (e & 7) * 8;
      bf16x8 kv = *(const bf16x8*)(kTg + ((size_t)bh * 64 + row) * Ssz + c * 64 + c0);
      #pragma unroll
      for (int j = 0; j < 8; ++j) kv[j] = (bf16_t)((float)kv[j] * wsh[c0 + j]);
      *(bf16x8*)&Kw[row * 64 + c0] = kv;
    }
  }
  __syncthreads();
  f32x4 acc[4];
  #pragma unroll
  for (int n = 0; n < 4; ++n) acc[n] = (f32x4){0.f, 0.f, 0.f, 0.f};
  #pragma unroll
  for (int kk = 0; kk < 2; ++kk) {
    bf16x8 af = *(const bf16x8*)&Vt[(w * 16 + l15) * 64 + kk * 32 + l4 * 8];
    #pragma unroll
    for (int n = 0; n < 4; ++n) {
      bf16x8 bfr = *(const bf16x8*)&Kw[(n * 16 + l15) * 64 + kk * 32 + l4 * 8];
      acc[n] = __builtin_amdgcn_mfma_f32_16x16x32_bf16(af, bfr, acc[n], 0, 0, 0);
    }
  }
  size_t gb = ((size_t)bh * NCH + c) * 4096;
  #pragma unroll
  for (int n = 0; n < 4; ++n)
    #pragma unroll
    for (int j = 0; j < 4; ++j) {
      int row = w * 16 + l4 * 4 + j;
      int col = n * 16 + l15;
      G[gb + (size_t)row * 64 + col] = (bf16_t)acc[n][j];
    }
  if (t < 64) {
    float s = 0.f;
    for (int s2 = 0; s2 < 64; ++s2) s += (float)Kw[t * 64 + s2];
    ng[((size_t)bh * NCH + c) * 64 + t] = s;
  }
}

/* ---------------- state scan ---------------- */
__global__ __launch_bounds__(256) void state_scan(const bf16_t* __restrict__ G,
                                                  const float* __restrict__ ng,
                                                  const float* __restrict__ decays,
                                                  bf16_t* __restrict__ CstB,
                                                  float* __restrict__ nst) {
  int gid = blockIdx.x;
  if (gid < 512) {
    int idx = gid * 256 + threadIdx.x;
    int bh = idx >> 12, e = idx & 4095;
    const float* d = decays + bh * NCH;
    float C = 0.f;
    #pragma unroll
    for (int c = 0; c < NCH; ++c) {
      size_t o = ((size_t)bh * NCH + c) * 4096 + e;
      CstB[o] = (bf16_t)C;
      C = d[c] * C + (float)G[o];
    }
  } else {
    int idx = (gid - 512) * 256 + threadIdx.x;
    int bh = idx >> 6, e = idx & 63;
    const float* d = decays + bh * NCH;
    float n = 0.f;
    #pragma unroll
    for (int c = 0; c < NCH; ++c) {
      size_t o = ((size_t)bh * NCH + c) * 64 + e;
      nst[o] = n;
      n = d[c] * n + ng[o];
    }
  }
}

/* ---------------- intra-chunk outputs + fused group-norm/out-gate ---------------- */
__global__ __launch_bounds__(256) void intra_mfma(const bf16_t* __restrict__ qkvo,
                                                  const bf16_t* __restrict__ vTg,
                                                  const bf16_t* __restrict__ CstB,
                                                  const float* __restrict__ nst,
                                                  const float* __restrict__ ifb,
                                                  const float* __restrict__ blocal,
                                                  const float* __restrict__ Mhat,
                                                  const float* __restrict__ mstart,
                                                  const float* __restrict__ mhg,
                                                  bf16_t* __restrict__ gated) {
  int bh = blockIdx.x >> 5, c = blockIdx.x & 31;
  int b = bh >> 3, h = bh & 7;
  __shared__ bf16_t qs[64 * 64];
  __shared__ bf16_t ks[64 * 64];
  __shared__ bf16_t vTs[64 * 64];
  __shared__ bf16_t Cs[64 * 64];
  __shared__ float nin[64], den_s[64], ssrc[64], sdst[64], esc[64];
  const int t = threadIdx.x, w = t >> 6, l = t & 63;
  const int l15 = l & 15, l4 = l >> 4;
  const size_t tok0 = (size_t)b * Ssz + c * Lc;
  const size_t cbase = ((size_t)bh * NCH + c) * 4096;

  if (t < 64) {
    nin[t] = nst[((size_t)bh * NCH + c) * 64 + t];
    float bt = blocal[(size_t)bh * Ssz + c * Lc + t];
    float Mh2 = Mhat[(size_t)bh * Ssz + c * Lc + t];
    float Mc = mstart[bh * NCH + c];
    float iv = ifb[(tok0 + t) * 16 + h];
    float mt = fmaxf(Mc + bt, Mh2);
    ssrc[t] = iv - bt;
    sdst[t] = bt - mt;
    esc[t]  = __expf(Mc + bt - mt);
  }
  {
    const int r = l >> 3, c8 = (l & 7) * 8;
    #pragma unroll
    for (int i = 0; i < 2; ++i) {
      int seg = w * 2 + i, row = seg * 8 + r;
      gload16(qkvo + (tok0 + row) * 2048 + h * 64 + c8,          &qs[seg * 512]);
      gload16(qkvo + (tok0 + row) * 2048 + 512 + h * 64 + c8,    &ks[seg * 512]);
      gload16(vTg + ((size_t)bh * 64 + row) * Ssz + c * 64 + c8, &vTs[seg * 512]);
      gload16(CstB + cbase + seg * 512 + l * 8,                  &Cs[seg * 512]);
    }
  }
  __syncthreads();

  f32x4 aS[4];
  #pragma unroll
  for (int n = 0; n < 4; ++n) aS[n] = (f32x4){0.f, 0.f, 0.f, 0.f};
  #pragma unroll
  for (int kk = 0; kk < 2; ++kk) {
    bf16x8 af = *(const bf16x8*)&qs[(w * 16 + l15) * 64 + kk * 32 + l4 * 8];
    #pragma unroll
    for (int n = 0; n < 4; ++n) {
      bf16x8 bfr = *(const bf16x8*)&ks[(n * 16 + l15) * 64 + kk * 32 + l4 * 8];
      aS[n] = __builtin_amdgcn_mfma_f32_16x16x32_bf16(af, bfr, aS[n], 0, 0, 0);
    }
  }
  {
    int row = w * 16 + (l >> 2);
    int c0 = (l & 3) * 16;
    float e = esc[row];
    #pragma unroll
    for (int i2 = 0; i2 < 2; ++i2) {
      bf16x8 v8 = *(const bf16x8*)&qs[row * 64 + c0 + i2 * 8];
      #pragma unroll
      for (int j = 0; j < 8; ++j) v8[j] = (bf16_t)((float)v8[j] * e);
      *(bf16x8*)&qs[row * 64 + c0 + i2 * 8] = v8;
    }
  }
  float rs[4] = {0.f, 0.f, 0.f, 0.f};
  #pragma unroll
  for (int n = 0; n < 4; ++n) {
    int col = n * 16 + l15;
    float es = ssrc[col];
    #pragma unroll
    for (int j = 0; j < 4; ++j) {
      int row = w * 16 + l4 * 4 + j;
      float p = (col <= row) ? aS[n][j] * __expf(es + sdst[row]) : 0.f;
      aS[n][j] = p;
      rs[j] += p;
    }
  }
  #pragma unroll
  for (int j = 0; j < 4; ++j) {
    rs[j] += __shfl_xor(rs[j], 1, 64);
    rs[j] += __shfl_xor(rs[j], 2, 64);
    rs[j] += __shfl_xor(rs[j], 4, 64);
    rs[j] += __shfl_xor(rs[j], 8, 64);
  }
  if (l15 == 0) {
    #pragma unroll
    for (int j = 0; j < 4; ++j) den_s[w * 16 + l4 * 4 + j] = rs[j];
  }
  __syncthreads();

  #pragma unroll
  for (int n = 0; n < 4; ++n)
    #pragma unroll
    for (int j = 0; j < 4; ++j)
      ks[(w * 16 + l4 * 4 + j) * 64 + n * 16 + l15] = (bf16_t)aS[n][j];

  {
    int row = w * 16 + (l >> 2);
    int c0 = (l & 3) * 16;
    float part = 0.f;
    #pragma unroll
    for (int i2 = 0; i2 < 16; ++i2)
      part += (float)qs[row * 64 + c0 + i2] * nin[c0 + i2];
    part += __shfl_xor(part, 1, 64);
    part += __shfl_xor(part, 2, 64);
    if ((l & 3) == 0)
      den_s[row] = fmaxf(fabsf(den_s[row] + part), 1.0f);
  }
  __syncthreads();

  f32x4 aO[4];
  #pragma unroll
  for (int n = 0; n < 4; ++n) aO[n] = (f32x4){0.f, 0.f, 0.f, 0.f};
  #pragma unroll
  for (int kk = 0; kk < 2; ++kk) {
    bf16x8 afP = *(const bf16x8*)&ks[(w * 16 + l15) * 64 + kk * 32 + l4 * 8];
    bf16x8 afQ = *(const bf16x8*)&qs[(w * 16 + l15) * 64 + kk * 32 + l4 * 8];
    #pragma unroll
    for (int n = 0; n < 4; ++n) {
      bf16x8 bV = *(const bf16x8*)&vTs[(n * 16 + l15) * 64 + kk * 32 + l4 * 8];
      bf16x8 bC = *(const bf16x8*)&Cs[(n * 16 + l15) * 64 + kk * 32 + l4 * 8];
      aO[n] = __builtin_amdgcn_mfma_f32_16x16x32_bf16(afP, bV, aO[n], 0, 0, 0);
      aO[n] = __builtin_amdgcn_mfma_f32_16x16x32_bf16(afQ, bC, aO[n], 0, 0, 0);
    }
  }

  /* fused per-row group-norm (64 cols in 16 lanes x 4 regs) + sigmoid(og)*mh_g */
  #pragma unroll
  for (int j = 0; j < 4; ++j) {
    int row = w * 16 + l4 * 4 + j;
    float rinv = 1.f / den_s[row];
    float ov[4];
    #pragma unroll
    for (int n = 0; n < 4; ++n) ov[n] = aO[n][j] * rinv;
    float s = ov[0] + ov[1] + ov[2] + ov[3];
    s += __shfl_xor(s, 1, 64); s += __shfl_xor(s, 2, 64);
    s += __shfl_xor(s, 4, 64); s += __shfl_xor(s, 8, 64);
    float mu = s * (1.f / 64.f);
    float s2 = 0.f;
    #pragma unroll
    for (int n = 0; n < 4; ++n) { float d = ov[n] - mu; s2 += d * d; }
    s2 += __shfl_xor(s2, 1, 64); s2 += __shfl_xor(s2, 2, 64);
    s2 += __shfl_xor(s2, 4, 64); s2 += __shfl_xor(s2, 8, 64);
    float rstd = rsqrtf(s2 * (1.f / 64.f) + 1e-5f);
    size_t tok = tok0 + row;
    #pragma unroll
    for (int n = 0; n < 4; ++n) {
      int colh = n * 16 + l15;
      float og = (float)qkvo[tok * 2048 + 1536 + h * 64 + colh];
      float hn = (ov[n] - mu) * rstd * mhg[h * 64 + colh];
      gated[tok * 512 + h * 64 + colh] = (bf16_t)(og * hn);
    }
  }
}

/* ---------------- launcher ---------------- */
extern "C" void kernel_launch(void* const* d_in, const int* in_sizes, int n_in,
                              void* d_out, int out_size, void* d_ws, size_t ws_size,
                              hipStream_t stream) {
  const float* x     = (const float*)d_in[0];
  const float* ln_g  = (const float*)d_in[1];
  const float* ln_b  = (const float*)d_in[2];
  const float* W_up  = (const float*)d_in[3];
  const float* W_down= (const float*)d_in[4];
  const float* Wq    = (const float*)d_in[5];
  const float* Wk    = (const float*)d_in[6];
  const float* Wv    = (const float*)d_in[7];
  const float* Wi    = (const float*)d_in[8];
  const float* bi    = (const float*)d_in[9];
  const float* Wf    = (const float*)d_in[10];
  const float* bfv   = (const float*)d_in[11];
  const float* Wo    = (const float*)d_in[12];
  const float* bo    = (const float*)d_in[13];
  const float* mh_g  = (const float*)d_in[14];
  const float* W_out = (const float*)d_in[15];

  char* ws = (char*)d_ws;
  bf16_t* hbuf   = (bf16_t*)(ws + OFF_H);
  bf16_t* wupT   = (bf16_t*)(ws + OFF_WUPT);
  bf16_t* wqxT   = (bf16_t*)(ws + OFF_WQX);
  bf16_t* wdownT = (bf16_t*)(ws + OFF_WDOWNT);
  bf16_t* wocT   = (bf16_t*)(ws + OFF_WOC);
  float*  biasA  = (float*)(ws + OFF_BIAS);
  bf16_t* ubuf   = (bf16_t*)(ws + OFF_U);
  bf16_t* qkvob  = (bf16_t*)(ws + OFF_QKVO);
  bf16_t* woutB  = (bf16_t*)(ws + OFF_WOUTB);
  bf16_t* kTg    = (bf16_t*)(ws + OFF_KT);
  bf16_t* vTg    = (bf16_t*)(ws + OFF_VT);
  float*  ifb    = (float*)(ws + OFF_IFB);
  float*  bloc   = (float*)(ws + OFF_BLOC);
  float*  Mh     = (float*)(ws + OFF_MHAT);
  float*  mst    = (float*)(ws + OFF_MST);
  float*  decays = (float*)(ws + OFF_DEC);
  float*  mendb  = (float*)(ws + OFF_MEND);
  float*  ngbuf  = (float*)(ws + OFF_NG);
  float*  nst    = (float*)(ws + OFF_NST);
  bf16_t* CstB   = (bf16_t*)(ws + OFF_CSTB);
  bf16_t* Gbuf   = (bf16_t*)(ws + OFF_G);
  bf16_t* gbuf   = (bf16_t*)(ws + OFF_GATED);

  dim3 tb(32, 8);
  transpose_cast<<<dim3(Isz / 32, Dsz / 32), tb, 0, stream>>>(W_up, wupT, Dsz, Isz, 1.f);
  transpose_cast<<<dim3(512 / 32, Isz / 32), tb, 0, stream>>>(Wq, wqxT,                    Isz, 512, 1.f);
  transpose_cast<<<dim3(512 / 32, Isz / 32), tb, 0, stream>>>(Wk, wqxT + (size_t)512*Isz,  Isz, 512, 0.125f);
  transpose_cast<<<dim3(512 / 32, Isz / 32), tb, 0, stream>>>(Wv, wqxT + (size_t)1024*Isz, Isz, 512, 1.f);
  transpose_cast<<<dim3(512 / 32, Isz / 32), tb, 0, stream>>>(Wo, wqxT + (size_t)1536*Isz, Isz, 512, 1.f);
  build_wift<<<96, 256, 0, stream>>>(Wi, Wf, wqxT + (size_t)2048 * Isz);
  hipMemsetAsync(wqxT + (size_t)2064 * Isz, 0, (size_t)(NQX - 2064) * Isz * sizeof(bf16_t), stream);
  transpose_cast<<<dim3(Dsz / 32, Isz / 32), tb, 0, stream>>>(W_down, wdownT, Isz, Dsz, 1.f);
  cast_bf16<<<(512 * 1536 + 255) / 256, 256, 0, stream>>>(W_out, woutB, 512 * 1536);
  build_bias<<<3, 256, 0, stream>>>(bo, bi, bfv, biasA);

  /* WocT(768,512) = wdownT @ woutB^T == (W_out @ W_down)^T */
  gemm_bt<<<dim3(512 / 128, Dsz / 128), 256, 0, stream>>>(wdownT, woutB, wocT, Dsz, 512, Isz);

  ln_kernel<<<NTOK, 256, 0, stream>>>(x, ln_g, ln_b, hbuf);

  gemm_mn<0><<<dim3(Isz / 128, NTOK / 256), 512, 0, stream>>>(hbuf, wupT, ubuf, nullptr, nullptr, nullptr, nullptr, NTOK, Isz, Dsz);
  /* fused qkvo + if-proj + kv-transpose epilogue */
  gemm_mn<5><<<dim3(NQX / 128, NTOK / 256), 512, 0, stream>>>(ubuf, wqxT, qkvob, biasA, kTg, vTg, ifb, NTOK, NQX, Isz);

  gates_a<<<NBH * NCH, 64, 0, stream>>>(ifb, bloc, Mh);
  gates_b<<<1, 32, 0, stream>>>(bloc, Mh, mst, decays, mendb);
  chunk_inc_mfma<<<NBH * NCH, 256, 0, stream>>>(kTg, vTg, ifb, bloc, mendb, Gbuf, ngbuf);
  state_scan<<<520, 256, 0, stream>>>(Gbuf, ngbuf, decays, CstB, nst);
  /* intra with fused group-norm + out-gate -> gated */
  intra_mfma<<<NBH * NCH, 256, 0, stream>>>(qkvob, vTg, CstB, nst, ifb, bloc, Mh, mst, mh_g, gbuf);

  /* fused: out = x + gated @ (W_out @ W_down), K=512 */
  gemm_mn<3><<<dim3(Dsz / 128, NTOK / 256), 512, 0, stream>>>(gbuf, wocT, (float*)d_out, x, nullptr, nullptr, nullptr, NTOK, Dsz, 512);
}